// Round 9
// baseline (9258.044 us; speedup 1.0000x reference)
//
#include <hip/hip_runtime.h>
#include <cstdio>
#include <cstdint>

// V=30000, E=512, H=512, T=32, B=64, L=512
// eg layout: [t][e4:128][b:64][4]   (64 MB)
// h  layout: [t][c4:128][b:64][4]   (64 MB per dir)
// em layout: [t][b][tag]            (4 MB)
// wpack: [dir][wg:256][ks:8][sec:2][kc:16][r:8][j:4]  (16 MB)
//   r = gate*2 + colL; global row = gate*512 + wg*2 + colL; k = ks*64+kc*4+j
// sync: ctr[dir][step][sub:8] (64B-strided). Producer: sc1 store -> vmcnt(0)
//   -> relaxed agent fetch_add to sub=wg&7 (32 adds/line). Consumer: 8
//   pollers, each waits its sub ==32. Cached h reads are value-identity safe
//   across replays (h is deterministic; unique address per t).
// R9: each WG handles BOTH directions (2 fwd + 2 bwd cols) in alternating
//   phases -> the other direction's compute hides the sync chain; e-proj
//   FMAs (register-only, operands preloaded) hide the h-fetch latency.

typedef float f32x4 __attribute__((ext_vector_type(4)));
typedef float f32x2 __attribute__((ext_vector_type(2)));

// ---------------------------------------------------------------------------
// K0: embedding gather -> eg[t][e4][b][4]
// ---------------------------------------------------------------------------
__global__ __launch_bounds__(512) void k_gather(
    const int* __restrict__ x, const float* __restrict__ emb,
    float4* __restrict__ eg4)
{
    const int t   = blockIdx.x;
    const int tid = threadIdx.x;
    __shared__ int xv[64];
    if (tid < 64) xv[tid] = x[tid * 512 + t];
    __syncthreads();
    #pragma unroll
    for (int i = 0; i < 16; ++i) {
        const int flat = i * 512 + tid;       // 0..8191
        const int b  = flat & 63;
        const int e4 = flat >> 6;             // 0..127
        const float4 v = *reinterpret_cast<const float4*>(
            emb + (size_t)xv[b] * 512 + e4 * 4);
        eg4[((size_t)t * 128 + e4) * 64 + b] = v;
    }
}

// ---------------------------------------------------------------------------
// K0b: pack weights: [dir][wg:256][ks:8][sec:2][kc:16][r:8][j:4]
// ---------------------------------------------------------------------------
__global__ __launch_bounds__(256) void k_pack(
    const float* __restrict__ wih_f, const float* __restrict__ whh_f,
    const float* __restrict__ wih_b, const float* __restrict__ whh_b,
    float* __restrict__ wpack)
{
    const int i = blockIdx.x * 256 + threadIdx.x;   // 0 .. 4194303
    const int j   = i & 3;
    const int r   = (i >> 2) & 7;
    const int kc  = (i >> 5) & 15;
    const int sec = (i >> 9) & 1;
    const int ks  = (i >> 10) & 7;
    const int wg  = (i >> 13) & 255;
    const int dir = (i >> 21) & 1;
    const int k   = ks * 64 + kc * 4 + j;           // 0..511
    const int g   = r >> 1, colL = r & 1;
    const int rg  = g * 512 + wg * 2 + colL;        // global gate row
    const float* wih = dir ? wih_b : wih_f;
    const float* whh = dir ? whh_b : whh_f;
    const float v = sec ? whh[(size_t)rg * 512 + k] : wih[(size_t)rg * 512 + k];
    wpack[i] = v;
}

// ---------------------------------------------------------------------------
// one direction's phase of step s (inlined twice per iteration)
// ---------------------------------------------------------------------------
__device__ __forceinline__ void lstm_phase(
    const int s, const int t, const int tp, const int tn2,
    const float4* __restrict__ eg4, const float4* __restrict__ HQ,
    float* __restrict__ HH, const float* __restrict__ wb,
    int* __restrict__ ctr, const float bias4[4],
    float eacc[8], f32x4 ov[16], float& cst,
    float (*part)[8][64], float (*hlds)[2],
    const int tid, const int b, const int ks, const int wg, const int colL)
{
    const float* wE = wb;
    const float* wH = wb + 512;

    // ---- wait for step s-1 producers (8-way counter tree) ----
    if (s > 0) {
        if (tid < 8) {
            const int* fp = ctr + ((size_t)(s - 1) * 8 + tid) * 16;
            while (__hip_atomic_load(fp, __ATOMIC_RELAXED,
                                     __HIP_MEMORY_SCOPE_AGENT) < 32)
                __builtin_amdgcn_s_sleep(1);
        }
        __syncthreads();
    }

    float acc[8];
    #pragma unroll
    for (int r = 0; r < 8; ++r) acc[r] = eacc[r];

    // ---- issue h loads (cached dwordx4) ----
    f32x4 hv[16];
    if (s > 0) {
        const float4* hq = HQ + ((size_t)tp * 128 + ks * 16) * 64 + b;
        #pragma unroll
        for (int kc = 0; kc < 16; ++kc)
            hv[kc] = *reinterpret_cast<const f32x4*>(hq + (size_t)kc * 64);
    }

    // ---- overlap: rebuild e-acc for step s+1 (register-only FMAs) ----
    if (s < 511) {
        #pragma unroll
        for (int r = 0; r < 8; ++r) eacc[r] = 0.f;
        #pragma unroll
        for (int kc = 0; kc < 16; ++kc) {
            const float* wp = wE + kc * 32;
            #pragma unroll
            for (int r = 0; r < 8; ++r) {
                eacc[r] = fmaf(wp[r * 4 + 0], ov[kc][0], eacc[r]);
                eacc[r] = fmaf(wp[r * 4 + 1], ov[kc][1], eacc[r]);
                eacc[r] = fmaf(wp[r * 4 + 2], ov[kc][2], eacc[r]);
                eacc[r] = fmaf(wp[r * 4 + 3], ov[kc][3], eacc[r]);
            }
        }
    }

    // ---- h-part FMAs ----
    if (s > 0) {
        #pragma unroll
        for (int kc = 0; kc < 16; ++kc) {
            const float* wp = wH + kc * 32;
            #pragma unroll
            for (int r = 0; r < 8; ++r) {
                acc[r] = fmaf(wp[r * 4 + 0], hv[kc][0], acc[r]);
                acc[r] = fmaf(wp[r * 4 + 1], hv[kc][1], acc[r]);
                acc[r] = fmaf(wp[r * 4 + 2], hv[kc][2], acc[r]);
                acc[r] = fmaf(wp[r * 4 + 3], hv[kc][3], acc[r]);
            }
        }
    }

    // ---- split-k reduce ----
    #pragma unroll
    for (int r = 0; r < 8; ++r) part[ks][r][b] = acc[r];
    __syncthreads();

    // ---- gates (tid<128: b x colL) ----
    if (tid < 128) {
        float g4[4];
        #pragma unroll
        for (int g = 0; g < 4; ++g) {
            const int r = g * 2 + colL;
            float v = bias4[g];
            #pragma unroll
            for (int w = 0; w < 8; ++w) v += part[w][r][b];
            g4[g] = v;
        }
        const float si = 1.f / (1.f + expf(-g4[0]));
        const float sf = 1.f / (1.f + expf(-g4[1]));
        const float tg = tanhf(g4[2]);
        const float so = 1.f / (1.f + expf(-g4[3]));
        cst = sf * cst + si * tg;
        hlds[b][colL] = so * tanhf(cst);
    }
    __syncthreads();

    // ---- wave0: sc1 store (dwordx2), drain, publish ----
    if (tid < 64) {
        f32x2 o;
        o[0] = hlds[tid][0]; o[1] = hlds[tid][1];
        float* dst = HH + (((size_t)t * 128 + (wg >> 1)) * 64 + tid) * 4
                        + (wg & 1) * 2;
        asm volatile("global_store_dwordx2 %0, %1, off sc1"
                     :: "v"(dst), "v"(o) : "memory");
        asm volatile("s_waitcnt vmcnt(0)" ::: "memory");
        if (tid == 0 && s < 511)
            __hip_atomic_fetch_add(ctr + ((size_t)s * 8 + (wg & 7)) * 16, 1,
                                   __ATOMIC_RELAXED, __HIP_MEMORY_SCOPE_AGENT);
    }

    // ---- refill e-operands for step s+2 (latency dangles into next phase) ----
    if (tn2 >= 0 && tn2 < 512) {
        const float4* ep = eg4 + ((size_t)tn2 * 128 + ks * 16) * 64 + b;
        #pragma unroll
        for (int kc = 0; kc < 16; ++kc)
            ov[kc] = *reinterpret_cast<const f32x4*>(ep + (size_t)kc * 64);
    }
}

// ---------------------------------------------------------------------------
// K1: fused-direction persistent BiLSTM. 256 WGs x 512 threads.
// WG owns fwd cols {2wg,2wg+1} and bwd cols {2wg,2wg+1}.
// ---------------------------------------------------------------------------
__global__ __launch_bounds__(512) void k_lstm(
    const float4* __restrict__ eg4, const float* __restrict__ wpack,
    const float* __restrict__ b_f, const float* __restrict__ b_b,
    float* __restrict__ h_f, float* __restrict__ h_b,
    int* __restrict__ bar)
{
    const int wg  = blockIdx.x;         // 0..255
    const int tid = threadIdx.x;
    const int b   = tid & 63;
    const int ks  = __builtin_amdgcn_readfirstlane(tid >> 6);
    const int colL = (tid >> 6) & 1;

    __shared__ float part[8][8][64];    // 16 KB
    __shared__ float hlds[64][2];

    const float4* HQf = reinterpret_cast<const float4*>(h_f);
    const float4* HQb = reinterpret_cast<const float4*>(h_b);
    const float* wbF = wpack + (size_t)((0 * 256 + wg) * 8 + ks) * 1024;
    const float* wbB = wpack + (size_t)((1 * 256 + wg) * 8 + ks) * 1024;
    int* ctrF = bar;
    int* ctrB = bar + 65536;

    float biasF[4] = {0,0,0,0}, biasB[4] = {0,0,0,0};
    if (tid < 128) {
        #pragma unroll
        for (int g = 0; g < 4; ++g) {
            biasF[g] = b_f[g * 512 + wg * 2 + colL];
            biasB[g] = b_b[g * 512 + wg * 2 + colL];
        }
    }
    float cstF = 0.f, cstB = 0.f;

    f32x4 ovF[16], ovB[16];
    float eaF[8], eaB[8];

    // prologue: e-proj for step 0, then preload operands for step 1
    {
        const float4* epF = eg4 + ((size_t)0 * 128 + ks * 16) * 64 + b;
        const float4* epB = eg4 + ((size_t)511 * 128 + ks * 16) * 64 + b;
        #pragma unroll
        for (int kc = 0; kc < 16; ++kc) {
            ovF[kc] = *reinterpret_cast<const f32x4*>(epF + (size_t)kc * 64);
            ovB[kc] = *reinterpret_cast<const f32x4*>(epB + (size_t)kc * 64);
        }
        #pragma unroll
        for (int r = 0; r < 8; ++r) { eaF[r] = 0.f; eaB[r] = 0.f; }
        #pragma unroll
        for (int kc = 0; kc < 16; ++kc) {
            const float* wpF = wbF + kc * 32;
            const float* wpB = wbB + kc * 32;
            #pragma unroll
            for (int r = 0; r < 8; ++r) {
                eaF[r] = fmaf(wpF[r*4+0], ovF[kc][0], eaF[r]);
                eaF[r] = fmaf(wpF[r*4+1], ovF[kc][1], eaF[r]);
                eaF[r] = fmaf(wpF[r*4+2], ovF[kc][2], eaF[r]);
                eaF[r] = fmaf(wpF[r*4+3], ovF[kc][3], eaF[r]);
                eaB[r] = fmaf(wpB[r*4+0], ovB[kc][0], eaB[r]);
                eaB[r] = fmaf(wpB[r*4+1], ovB[kc][1], eaB[r]);
                eaB[r] = fmaf(wpB[r*4+2], ovB[kc][2], eaB[r]);
                eaB[r] = fmaf(wpB[r*4+3], ovB[kc][3], eaB[r]);
            }
        }
        const float4* epF1 = eg4 + ((size_t)1 * 128 + ks * 16) * 64 + b;
        const float4* epB1 = eg4 + ((size_t)510 * 128 + ks * 16) * 64 + b;
        #pragma unroll
        for (int kc = 0; kc < 16; ++kc) {
            ovF[kc] = *reinterpret_cast<const f32x4*>(epF1 + (size_t)kc * 64);
            ovB[kc] = *reinterpret_cast<const f32x4*>(epB1 + (size_t)kc * 64);
        }
    }

    for (int s = 0; s < 512; ++s) {
        // forward phase: t = s
        lstm_phase(s, s, s - 1, s + 2,
                   eg4, HQf, h_f, wbF, ctrF, biasF,
                   eaF, ovF, cstF, part, hlds, tid, b, ks, wg, colL);
        // backward phase: t = 511-s
        lstm_phase(s, 511 - s, 512 - s, 509 - s,
                   eg4, HQb, h_b, wbB, ctrB, biasB,
                   eaB, ovB, cstB, part, hlds, tid, b, ks, wg, colL);
    }
}

// ---------------------------------------------------------------------------
// K2: emissions  em[t][b][tag] = [hf;hb](t,b,:) . W[tag][:] + bias
// ---------------------------------------------------------------------------
__global__ __launch_bounds__(256) void k_em(
    const float* __restrict__ hf, const float* __restrict__ hb,
    const float* __restrict__ Wm, const float* __restrict__ bias,
    float* __restrict__ em)
{
    const int t   = blockIdx.x;
    const int tid = threadIdx.x;
    const int b   = tid & 63;
    const int tg  = tid >> 6;          // 0..3 -> tags [tg*8, tg*8+8)
    __shared__ float Wl[128][33];
    float acc[8] = {};

    for (int ch = 0; ch < 8; ++ch) {
        {
            const int tag = tid >> 3;   // 0..31
            const int kq  = tid & 7;    // 0..7
            const float* src = Wm + (size_t)tag * 1024 + ch * 128 + kq * 16;
            #pragma unroll
            for (int ii = 0; ii < 4; ++ii) {
                const float4 v = *reinterpret_cast<const float4*>(src + ii * 4);
                const int k0 = kq * 16 + ii * 4;
                Wl[k0 + 0][tag] = v.x; Wl[k0 + 1][tag] = v.y;
                Wl[k0 + 2][tag] = v.z; Wl[k0 + 3][tag] = v.w;
            }
        }
        __syncthreads();
        const float4* hsrc4 = (ch < 4)
            ? (reinterpret_cast<const float4*>(hf) + ((size_t)t * 128 + ch * 32) * 64 + b)
            : (reinterpret_cast<const float4*>(hb) + ((size_t)t * 128 + (ch - 4) * 32) * 64 + b);
        #pragma unroll 4
        for (int c4l = 0; c4l < 32; ++c4l) {
            const float4 h4 = hsrc4[(size_t)c4l * 64];
            const float ha[4] = {h4.x, h4.y, h4.z, h4.w};
            #pragma unroll
            for (int j = 0; j < 4; ++j)
                #pragma unroll
                for (int jt = 0; jt < 8; ++jt)
                    acc[jt] = fmaf(ha[j], Wl[c4l * 4 + j][tg * 8 + jt], acc[jt]);
        }
        __syncthreads();
    }

    #pragma unroll
    for (int jt = 0; jt < 8; ++jt) {
        const int tag = tg * 8 + jt;
        em[((size_t)t * 64 + b) * 32 + tag] = acc[jt] + bias[tag];
    }
}

// ---------------------------------------------------------------------------
// K3: Viterbi forward + backtrace, one wave per batch row.
// ---------------------------------------------------------------------------
__global__ __launch_bounds__(64) void k_vit(
    const float* __restrict__ em, const float* __restrict__ startv,
    const float* __restrict__ endv, const float* __restrict__ trans,
    int* __restrict__ out)
{
    const int b    = blockIdx.x;
    const int lane = threadIdx.x;
    const int c    = lane & 31;
    const bool act = lane < 32;
    __shared__ unsigned char hist[511][32];
    __shared__ int outb[512];

    float tr[32];
    #pragma unroll 8
    for (int p = 0; p < 32; ++p) tr[p] = trans[p * 32 + c];

    float s = act ? (startv[c] + em[(size_t)b * 32 + c]) : -1e30f;

    for (int t = 1; t < 512; ++t) {
        const float emc = act ? em[((size_t)t * 64 + b) * 32 + c] : 0.f;
        float m = -1e30f; int arg = 0;
        #pragma unroll 8
        for (int p = 0; p < 32; ++p) {
            const float v = __shfl(s, p) + tr[p] + emc;   // (s+tr)+em, ref order
            if (v > m) { m = v; arg = p; }                // strict > => first max
        }
        if (act) { s = m; hist[t - 1][c] = (unsigned char)arg; }
    }

    s = act ? (s + endv[c]) : -1e30f;
    int idx = act ? c : 63;
    #pragma unroll
    for (int off = 32; off >= 1; off >>= 1) {
        const float om = __shfl_down(s, off);
        const int   oi = __shfl_down(idx, off);
        if (om > s || (om == s && oi < idx)) { s = om; idx = oi; }
    }
    idx = __shfl(idx, 0);

    if (lane == 0) {
        int tag = idx;
        outb[511] = tag;
        for (int t = 510; t >= 0; --t) { tag = hist[t][tag]; outb[t] = tag; }
    }
    __syncthreads();
    for (int i = lane; i < 512; i += 64) out[(size_t)b * 512 + i] = outb[i];
}

// ---------------------------------------------------------------------------
extern "C" void kernel_launch(void* const* d_in, const int* in_sizes, int n_in,
                              void* d_out, int out_size, void* d_ws, size_t ws_size,
                              hipStream_t stream)
{
    const int*   x      = (const int*)d_in[0];
    const float* emb    = (const float*)d_in[1];
    const float* w_ih_f = (const float*)d_in[2];
    const float* w_hh_f = (const float*)d_in[3];
    const float* b_f    = (const float*)d_in[4];
    const float* w_ih_b = (const float*)d_in[5];
    const float* w_hh_b = (const float*)d_in[6];
    const float* b_b    = (const float*)d_in[7];
    const float* Wm     = (const float*)d_in[8];
    const float* bvec   = (const float*)d_in[9];
    const float* startv = (const float*)d_in[10];
    const float* endv   = (const float*)d_in[11];
    const float* trans  = (const float*)d_in[12];
    int* out = (int*)d_out;

    float* ws    = (float*)d_ws;
    float* eg    = ws;                          // 16,777,216 f32 (64 MB)
    float* h_f   = ws + 16777216;               // 16,777,216 f32
    float* h_b   = ws + 33554432;               // 16,777,216 f32
    float* em    = ws + 50331648;               //  1,048,576 f32
    float* wpack = ws + 51380224;               //  4,194,304 f32 (16 MB)
    int*   bar   = (int*)(ws + 55574528);       //  131,072 ints (512 KB)

    const size_t need = (size_t)(55574528 + 131072) * 4;
    if (ws_size < need) {
        fprintf(stderr, "kernel_launch: ws too small: %zu < %zu\n", ws_size, need);
        return;
    }

    (void)hipMemsetAsync(bar, 0, 524288, stream);
    k_gather<<<dim3(512),   512, 0, stream>>>(x, emb, (float4*)eg);
    k_pack  <<<dim3(16384), 256, 0, stream>>>(w_ih_f, w_hh_f, w_ih_b, w_hh_b, wpack);
    k_lstm  <<<dim3(256),   512, 0, stream>>>((const float4*)eg, wpack, b_f, b_b,
                                              h_f, h_b, bar);
    k_em    <<<dim3(512),   256, 0, stream>>>(h_f, h_b, Wm, bvec, em);
    k_vit   <<<dim3(64),     64, 0, stream>>>(em, startv, endv, trans, out);
}

// Round 10
// 8749.592 us; speedup vs baseline: 1.0581x; 1.0581x over previous
//
#include <hip/hip_runtime.h>
#include <cstdio>
#include <cstdint>

// V=30000, E=512, H=512, T=32, B=64, L=512
// eg layout: [t][e4:128][b:64][4]   (64 MB)
// h  layout: [t][c4:128][b:64][4]   (64 MB per dir)
// em layout: [t][b][tag]            (4 MB)
// wpack: [dir][wg:128][ks:8][sec:2][kc:16][r:16][j:4]  (16 MB)
// sync: ctr[dir][step][sub:8] (64 B apart). Producer wg: dwordx4 sc1 h-store
//   -> vmcnt(0) -> one relaxed agent fetch_add to sub = wg>>4 (16 adds/line).
// Consumer: PER-WAVE gating - wave ks polls ONLY sub-counter ks (its 16
//   producers cover exactly its k-range [64ks,64ks+64)). All 64 lanes poll
//   the same address (1 transaction); no WG-wide barrier on the wait path.

typedef float f32x4 __attribute__((ext_vector_type(4)));

// ---------------------------------------------------------------------------
// K0: embedding gather -> eg[t][e4][b][4]
// ---------------------------------------------------------------------------
__global__ __launch_bounds__(512) void k_gather(
    const int* __restrict__ x, const float* __restrict__ emb,
    float4* __restrict__ eg4)
{
    const int t   = blockIdx.x;
    const int tid = threadIdx.x;
    __shared__ int xv[64];
    if (tid < 64) xv[tid] = x[tid * 512 + t];
    __syncthreads();
    #pragma unroll
    for (int i = 0; i < 16; ++i) {
        const int flat = i * 512 + tid;       // 0..8191
        const int b  = flat & 63;
        const int e4 = flat >> 6;             // 0..127
        const float4 v = *reinterpret_cast<const float4*>(
            emb + (size_t)xv[b] * 512 + e4 * 4);
        eg4[((size_t)t * 128 + e4) * 64 + b] = v;
    }
}

// ---------------------------------------------------------------------------
// K0b: pack weights into per-wave contiguous blocks
// ---------------------------------------------------------------------------
__global__ __launch_bounds__(256) void k_pack(
    const float* __restrict__ wih_f, const float* __restrict__ whh_f,
    const float* __restrict__ wih_b, const float* __restrict__ whh_b,
    float* __restrict__ wpack)
{
    const int i = blockIdx.x * 256 + threadIdx.x;   // 0 .. 4194303
    const int j   = i & 3;
    const int r   = (i >> 2) & 15;
    const int kc  = (i >> 6) & 15;
    const int sec = (i >> 10) & 1;
    const int ks  = (i >> 11) & 7;
    const int wg  = (i >> 14) & 127;
    const int dir = (i >> 21) & 1;
    const int k   = ks * 64 + kc * 4 + j;           // 0..511
    const int g   = r >> 2, cl = r & 3;
    const int rg  = g * 512 + wg * 4 + cl;          // global gate row
    const float* wih = dir ? wih_b : wih_f;
    const float* whh = dir ? whh_b : whh_f;
    const float v = sec ? whh[(size_t)rg * 512 + k] : wih[(size_t)rg * 512 + k];
    wpack[i] = v;
}

// ---------------------------------------------------------------------------
// 64-k dot block: q = per-lane float4 stream (cached), w = packed weights
// ---------------------------------------------------------------------------
__device__ __forceinline__ void dot64(const float4* __restrict__ q,
                                      const float* __restrict__ w,
                                      float acc[16])
{
    float4 v[16];
    #pragma unroll
    for (int kc = 0; kc < 16; ++kc) v[kc] = q[(size_t)kc * 64];
    #pragma unroll
    for (int kc = 0; kc < 16; ++kc) {
        const float* wp = w + kc * 64;
        #pragma unroll
        for (int r = 0; r < 16; ++r) {
            acc[r] = fmaf(wp[r * 4 + 0], v[kc].x, acc[r]);
            acc[r] = fmaf(wp[r * 4 + 1], v[kc].y, acc[r]);
            acc[r] = fmaf(wp[r * 4 + 2], v[kc].z, acc[r]);
            acc[r] = fmaf(wp[r * 4 + 3], v[kc].w, acc[r]);
        }
    }
}

// ---------------------------------------------------------------------------
// K1: persistent BiLSTM recurrence. 256 WGs (128/dir) x 512 threads.
// WG owns 4 h-cols (16 gate rows). lane = b, wave = k-slice (split-k x8).
// Per-wave dataflow sync (see header comment).
// ---------------------------------------------------------------------------
__global__ __launch_bounds__(512) void k_lstm(
    const float4* __restrict__ eg4, const float* __restrict__ wpack,
    const float* __restrict__ b_f, const float* __restrict__ b_b,
    float* __restrict__ h_f, float* __restrict__ h_b,
    int* __restrict__ bar)
{
    const int bid = blockIdx.x;
    const int dir = bid >> 7;
    const int wg  = bid & 127;
    float* HH  = dir ? h_b : h_f;
    float4* HH4 = reinterpret_cast<float4*>(HH);
    const float4* HQ = reinterpret_cast<const float4*>(HH);
    const float* BS  = dir ? b_b : b_f;
    int* ctr = bar + (size_t)dir * 512 * 8 * 16;   // [step][sub:8] x 16 ints

    const int tid = threadIdx.x;
    const int b   = tid & 63;
    const int ks  = __builtin_amdgcn_readfirstlane(tid >> 6);

    __shared__ float part[8][16][64];   // 32 KB split-k exchange
    __shared__ float hlds[64][5];       // padded h staging for coalesced store

    const float* wbase = wpack + (size_t)((dir * 128 + wg) * 8 + ks) * 2048;
    const float* wE = wbase;            // sec 0
    const float* wH = wbase + 1024;     // sec 1

    const int col = (tid >> 6) & 3;     // gate-phase column (tid<256)
    float bias4[4] = {0.f, 0.f, 0.f, 0.f};
    if (tid < 256) {
        #pragma unroll
        for (int g = 0; g < 4; ++g) bias4[g] = BS[g * 512 + wg * 4 + col];
    }
    float cst = 0.f;

    // prologue: e-part for step 0
    float eacc[16];
    #pragma unroll
    for (int r = 0; r < 16; ++r) eacc[r] = 0.f;
    {
        const int t0 = dir ? 511 : 0;
        dot64(eg4 + ((size_t)t0 * 128 + ks * 16) * 64 + b, wE, eacc);
    }

    for (int s = 0; s < 512; ++s) {
        const int t = dir ? (511 - s) : s;
        float acc[16];
        #pragma unroll
        for (int r = 0; r < 16; ++r) acc[r] = eacc[r];

        // ---- per-wave wait: only THIS wave's 16 producers ----
        if (s > 0) {
            const int* fp = ctr + ((size_t)(s - 1) * 8 + ks) * 16;
            while (__hip_atomic_load(fp, __ATOMIC_RELAXED,
                                     __HIP_MEMORY_SCOPE_AGENT) < 16)
                __builtin_amdgcn_s_sleep(1);
            const int tp = dir ? (t + 1) : (t - 1);
            dot64(HQ + ((size_t)tp * 128 + ks * 16) * 64 + b, wH, acc);
        }

        // ---- split-k reduce ----
        #pragma unroll
        for (int r = 0; r < 16; ++r) part[ks][r][b] = acc[r];
        __syncthreads();                 // sync1: part ready

        // ---- gates -> hlds ----
        if (tid < 256) {
            float g4[4];
            #pragma unroll
            for (int g = 0; g < 4; ++g) {
                const int r = g * 4 + col;
                float v = bias4[g];
                #pragma unroll
                for (int w = 0; w < 8; ++w) v += part[w][r][b];
                g4[g] = v;
            }
            const float si = 1.f / (1.f + expf(-g4[0]));
            const float sf = 1.f / (1.f + expf(-g4[1]));
            const float tg = tanhf(g4[2]);
            const float so = 1.f / (1.f + expf(-g4[3]));
            cst = sf * cst + si * tg;
            hlds[b][col] = so * tanhf(cst);
        }
        __syncthreads();                 // sync2: hlds ready, part consumed

        // ---- wave0: coalesced sc1 store, drain, publish to sub wg>>4 ----
        if (tid < 64) {
            f32x4 o;
            o[0] = hlds[tid][0]; o[1] = hlds[tid][1];
            o[2] = hlds[tid][2]; o[3] = hlds[tid][3];
            float4* dst = HH4 + ((size_t)t * 128 + wg) * 64 + tid;
            asm volatile("global_store_dwordx4 %0, %1, off sc1"
                         :: "v"(dst), "v"(o) : "memory");
            asm volatile("s_waitcnt vmcnt(0)" ::: "memory");
            if (tid == 0 && s < 511)
                __hip_atomic_fetch_add(
                    ctr + ((size_t)s * 8 + (wg >> 4)) * 16, 1,
                    __ATOMIC_RELAXED, __HIP_MEMORY_SCOPE_AGENT);
        }

        // ---- e-part for step s+1 (off critical path) ----
        if (s < 511) {
            const int tn = dir ? (t - 1) : (t + 1);
            #pragma unroll
            for (int r = 0; r < 16; ++r) eacc[r] = 0.f;
            dot64(eg4 + ((size_t)tn * 128 + ks * 16) * 64 + b, wE, eacc);
        }
    }
}

// ---------------------------------------------------------------------------
// K2: emissions  em[t][b][tag] = [hf;hb](t,b,:) . W[tag][:] + bias
// ---------------------------------------------------------------------------
__global__ __launch_bounds__(256) void k_em(
    const float* __restrict__ hf, const float* __restrict__ hb,
    const float* __restrict__ Wm, const float* __restrict__ bias,
    float* __restrict__ em)
{
    const int t   = blockIdx.x;
    const int tid = threadIdx.x;
    const int b   = tid & 63;
    const int tg  = tid >> 6;          // 0..3 -> tags [tg*8, tg*8+8)
    __shared__ float Wl[128][33];
    float acc[8] = {};

    for (int ch = 0; ch < 8; ++ch) {
        {
            const int tag = tid >> 3;   // 0..31
            const int kq  = tid & 7;    // 0..7
            const float* src = Wm + (size_t)tag * 1024 + ch * 128 + kq * 16;
            #pragma unroll
            for (int ii = 0; ii < 4; ++ii) {
                const float4 v = *reinterpret_cast<const float4*>(src + ii * 4);
                const int k0 = kq * 16 + ii * 4;
                Wl[k0 + 0][tag] = v.x; Wl[k0 + 1][tag] = v.y;
                Wl[k0 + 2][tag] = v.z; Wl[k0 + 3][tag] = v.w;
            }
        }
        __syncthreads();
        const float4* hsrc4 = (ch < 4)
            ? (reinterpret_cast<const float4*>(hf) + ((size_t)t * 128 + ch * 32) * 64 + b)
            : (reinterpret_cast<const float4*>(hb) + ((size_t)t * 128 + (ch - 4) * 32) * 64 + b);
        #pragma unroll 4
        for (int c4l = 0; c4l < 32; ++c4l) {
            const float4 h4 = hsrc4[(size_t)c4l * 64];
            const float ha[4] = {h4.x, h4.y, h4.z, h4.w};
            #pragma unroll
            for (int j = 0; j < 4; ++j)
                #pragma unroll
                for (int jt = 0; jt < 8; ++jt)
                    acc[jt] = fmaf(ha[j], Wl[c4l * 4 + j][tg * 8 + jt], acc[jt]);
        }
        __syncthreads();
    }

    #pragma unroll
    for (int jt = 0; jt < 8; ++jt) {
        const int tag = tg * 8 + jt;
        em[((size_t)t * 64 + b) * 32 + tag] = acc[jt] + bias[tag];
    }
}

// ---------------------------------------------------------------------------
// K3: Viterbi forward + backtrace, one wave per batch row.
// ---------------------------------------------------------------------------
__global__ __launch_bounds__(64) void k_vit(
    const float* __restrict__ em, const float* __restrict__ startv,
    const float* __restrict__ endv, const float* __restrict__ trans,
    int* __restrict__ out)
{
    const int b    = blockIdx.x;
    const int lane = threadIdx.x;
    const int c    = lane & 31;
    const bool act = lane < 32;
    __shared__ unsigned char hist[511][32];
    __shared__ int outb[512];

    float tr[32];
    #pragma unroll 8
    for (int p = 0; p < 32; ++p) tr[p] = trans[p * 32 + c];

    float s = act ? (startv[c] + em[(size_t)b * 32 + c]) : -1e30f;

    for (int t = 1; t < 512; ++t) {
        const float emc = act ? em[((size_t)t * 64 + b) * 32 + c] : 0.f;
        float m = -1e30f; int arg = 0;
        #pragma unroll 8
        for (int p = 0; p < 32; ++p) {
            const float v = __shfl(s, p) + tr[p] + emc;   // (s+tr)+em, ref order
            if (v > m) { m = v; arg = p; }                // strict > => first max
        }
        if (act) { s = m; hist[t - 1][c] = (unsigned char)arg; }
    }

    s = act ? (s + endv[c]) : -1e30f;
    int idx = act ? c : 63;
    #pragma unroll
    for (int off = 32; off >= 1; off >>= 1) {
        const float om = __shfl_down(s, off);
        const int   oi = __shfl_down(idx, off);
        if (om > s || (om == s && oi < idx)) { s = om; idx = oi; }
    }
    idx = __shfl(idx, 0);

    if (lane == 0) {
        int tag = idx;
        outb[511] = tag;
        for (int t = 510; t >= 0; --t) { tag = hist[t][tag]; outb[t] = tag; }
    }
    __syncthreads();
    for (int i = lane; i < 512; i += 64) out[(size_t)b * 512 + i] = outb[i];
}

// ---------------------------------------------------------------------------
extern "C" void kernel_launch(void* const* d_in, const int* in_sizes, int n_in,
                              void* d_out, int out_size, void* d_ws, size_t ws_size,
                              hipStream_t stream)
{
    const int*   x      = (const int*)d_in[0];
    const float* emb    = (const float*)d_in[1];
    const float* w_ih_f = (const float*)d_in[2];
    const float* w_hh_f = (const float*)d_in[3];
    const float* b_f    = (const float*)d_in[4];
    const float* w_ih_b = (const float*)d_in[5];
    const float* w_hh_b = (const float*)d_in[6];
    const float* b_b    = (const float*)d_in[7];
    const float* Wm     = (const float*)d_in[8];
    const float* bvec   = (const float*)d_in[9];
    const float* startv = (const float*)d_in[10];
    const float* endv   = (const float*)d_in[11];
    const float* trans  = (const float*)d_in[12];
    int* out = (int*)d_out;

    float* ws    = (float*)d_ws;
    float* eg    = ws;                          // 16,777,216 f32 (64 MB)
    float* h_f   = ws + 16777216;               // 16,777,216 f32
    float* h_b   = ws + 33554432;               // 16,777,216 f32
    float* em    = ws + 50331648;               //  1,048,576 f32
    float* wpack = ws + 51380224;               //  4,194,304 f32 (16 MB)
    int*   bar   = (int*)(ws + 55574528);       //  131,072 ints (512 KB)

    const size_t need = (size_t)(55574528 + 131072) * 4;
    if (ws_size < need) {
        fprintf(stderr, "kernel_launch: ws too small: %zu < %zu\n", ws_size, need);
        return;
    }

    (void)hipMemsetAsync(bar, 0, 524288, stream);
    k_gather<<<dim3(512),   512, 0, stream>>>(x, emb, (float4*)eg);
    k_pack  <<<dim3(16384), 256, 0, stream>>>(w_ih_f, w_hh_f, w_ih_b, w_hh_b, wpack);
    k_lstm  <<<dim3(256),   512, 0, stream>>>((const float4*)eg, wpack, b_f, b_b,
                                              h_f, h_b, bar);
    k_em    <<<dim3(512),   256, 0, stream>>>(h_f, h_b, Wm, bvec, em);
    k_vit   <<<dim3(64),     64, 0, stream>>>(em, startv, endv, trans, out);
}

// Round 11
// 8073.810 us; speedup vs baseline: 1.1467x; 1.0837x over previous
//
#include <hip/hip_runtime.h>
#include <cstdio>
#include <cstdint>

// V=30000, E=512, H=512, T=32, B=64, L=512
// eg layout: [t][e4:128][b:64][4]   (64 MB)
// h  layout: [t][c2:256][b:64][2]   (64 MB per dir)  c2 = col/2
// em layout: [t][b][tag]            (4 MB)
// wpack: [dir][wg:256][ks:4][sec:2][kc:32][r:8][j:4]  (16 MB)
//   r = gate*2 + colL; global row = gate*512 + wg*2 + colL; k = ks*128+kc*4+j
// R11: weights staged ONCE into LDS (8 KB/wave) - removes the per-step
//   global weight refetch that stalled R4-R10 at ~25% VALUBusy. 512 WGs of
//   256 threads (2 WGs/CU) so co-resident WGs hide each other's sync stalls.
// sync: ctr[dir][step][sub:4] 64B-strided. Producer wg: dwordx2 sc1 h-store
//   (contiguous 512B/wave) -> vmcnt(0) -> fetch_add to sub=wg>>6.
//   Consumer wave ks polls sub ks (its 64 producers) until ==64.

typedef float f32x4 __attribute__((ext_vector_type(4)));
typedef float f32x2 __attribute__((ext_vector_type(2)));

// ---------------------------------------------------------------------------
// K0: embedding gather -> eg[t][e4][b][4]
// ---------------------------------------------------------------------------
__global__ __launch_bounds__(512) void k_gather(
    const int* __restrict__ x, const float* __restrict__ emb,
    float4* __restrict__ eg4)
{
    const int t   = blockIdx.x;
    const int tid = threadIdx.x;
    __shared__ int xv[64];
    if (tid < 64) xv[tid] = x[tid * 512 + t];
    __syncthreads();
    #pragma unroll
    for (int i = 0; i < 16; ++i) {
        const int flat = i * 512 + tid;       // 0..8191
        const int b  = flat & 63;
        const int e4 = flat >> 6;             // 0..127
        const float4 v = *reinterpret_cast<const float4*>(
            emb + (size_t)xv[b] * 512 + e4 * 4);
        eg4[((size_t)t * 128 + e4) * 64 + b] = v;
    }
}

// ---------------------------------------------------------------------------
// K0b: pack weights: [dir][wg:256][ks:4][sec:2][kc:32][r:8][j:4]
// ---------------------------------------------------------------------------
__global__ __launch_bounds__(256) void k_pack(
    const float* __restrict__ wih_f, const float* __restrict__ whh_f,
    const float* __restrict__ wih_b, const float* __restrict__ whh_b,
    float* __restrict__ wpack)
{
    const int i = blockIdx.x * 256 + threadIdx.x;   // 0 .. 4194303
    const int j   = i & 3;
    const int r   = (i >> 2) & 7;
    const int kc  = (i >> 5) & 31;
    const int sec = (i >> 10) & 1;
    const int ks  = (i >> 11) & 3;
    const int wg  = (i >> 13) & 255;
    const int dir = (i >> 21) & 1;
    const int k   = ks * 128 + kc * 4 + j;          // 0..511
    const int g   = r >> 1, colL = r & 1;
    const int rg  = g * 512 + wg * 2 + colL;        // global gate row
    const float* wih = dir ? wih_b : wih_f;
    const float* whh = dir ? whh_b : whh_f;
    const float v = sec ? whh[(size_t)rg * 512 + k] : wih[(size_t)rg * 512 + k];
    wpack[i] = v;
}

// ---------------------------------------------------------------------------
// K1: persistent BiLSTM recurrence. 512 WGs (256/dir) x 256 threads (4 waves).
// WG owns 2 h-cols (8 gate rows). lane = b, wave = k-slice (split-k x4).
// Weights in LDS (staged once); broadcast ds_read_b128 in the dot loops.
// ---------------------------------------------------------------------------
__global__ __launch_bounds__(256, 2) void k_lstm(
    const float4* __restrict__ eg4, const float* __restrict__ wpack,
    const float* __restrict__ b_f, const float* __restrict__ b_b,
    float* __restrict__ h_f, float* __restrict__ h_b,
    int* __restrict__ bar)
{
    const int bid = blockIdx.x;
    const int dir = bid >> 8;
    const int wg  = bid & 255;
    float* HH        = dir ? h_b : h_f;
    const float* BS  = dir ? b_b : b_f;
    int* ctr = bar + (size_t)dir * 512 * 4 * 16;   // [step][sub:4] x 16 ints

    const int tid = threadIdx.x;
    const int b   = tid & 63;
    const int ks  = __builtin_amdgcn_readfirstlane(tid >> 6);   // 0..3

    __shared__ float wsm[4][2048];     // 32 KB: per-wave weights (e at 0, h at 1024)
    __shared__ float part[4][8][64];   // 8 KB split-k exchange
    __shared__ float hlds[64][2];      // h staging for coalesced store

    // ---- stage this wave's weights into LDS (once) ----
    {
        const float4* wsrc = reinterpret_cast<const float4*>(
            wpack + (size_t)((dir * 256 + wg) * 4 + ks) * 2048);
        float4* wdst = reinterpret_cast<float4*>(&wsm[ks][0]);
        #pragma unroll
        for (int i = 0; i < 8; ++i)
            wdst[i * 64 + b] = wsrc[i * 64 + b];
    }
    __syncthreads();

    const int colL = (tid >> 6) & 1;    // gate-phase col (tid<128)
    float bias4[4] = {0.f, 0.f, 0.f, 0.f};
    if (tid < 128) {
        #pragma unroll
        for (int g = 0; g < 4; ++g) bias4[g] = BS[g * 512 + wg * 2 + colL];
    }
    float cst = 0.f;

    // prologue: e-part for step 0 (weights from LDS)
    float eacc[8];
    #pragma unroll
    for (int r = 0; r < 8; ++r) eacc[r] = 0.f;
    {
        const int t0 = dir ? 511 : 0;
        const float4* ep = eg4 + ((size_t)t0 * 128 + ks * 32) * 64 + b;
        float4 ev[32];
        #pragma unroll
        for (int kc = 0; kc < 32; ++kc) ev[kc] = ep[(size_t)kc * 64];
        #pragma unroll
        for (int kc = 0; kc < 32; ++kc) {
            #pragma unroll
            for (int r = 0; r < 8; ++r) {
                const f32x4 w4 = *reinterpret_cast<const f32x4*>(
                    &wsm[ks][kc * 32 + r * 4]);
                eacc[r] = fmaf(w4[0], ev[kc].x, eacc[r]);
                eacc[r] = fmaf(w4[1], ev[kc].y, eacc[r]);
                eacc[r] = fmaf(w4[2], ev[kc].z, eacc[r]);
                eacc[r] = fmaf(w4[3], ev[kc].w, eacc[r]);
            }
        }
    }

    for (int s = 0; s < 512; ++s) {
        const int t = dir ? (511 - s) : s;
        float acc[8];
        #pragma unroll
        for (int r = 0; r < 8; ++r) acc[r] = eacc[r];

        // ---- per-wave wait on sub-counter ks, then h-dot (LDS weights) ----
        if (s > 0) {
            const int* fp = ctr + ((size_t)(s - 1) * 4 + ks) * 16;
            while (__hip_atomic_load(fp, __ATOMIC_RELAXED,
                                     __HIP_MEMORY_SCOPE_AGENT) < 64)
                __builtin_amdgcn_s_sleep(1);

            const int tp = dir ? (t + 1) : (t - 1);
            const f32x2* hq = reinterpret_cast<const f32x2*>(HH)
                              + ((size_t)tp * 256 + ks * 64) * 64 + b;
            f32x2 hv[64];
            #pragma unroll
            for (int kq = 0; kq < 64; ++kq) hv[kq] = hq[(size_t)kq * 64];

            #pragma unroll
            for (int kc = 0; kc < 32; ++kc) {
                const float h0 = hv[kc * 2][0],     h1 = hv[kc * 2][1];
                const float h2 = hv[kc * 2 + 1][0], h3 = hv[kc * 2 + 1][1];
                #pragma unroll
                for (int r = 0; r < 8; ++r) {
                    const f32x4 w4 = *reinterpret_cast<const f32x4*>(
                        &wsm[ks][1024 + kc * 32 + r * 4]);
                    acc[r] = fmaf(w4[0], h0, acc[r]);
                    acc[r] = fmaf(w4[1], h1, acc[r]);
                    acc[r] = fmaf(w4[2], h2, acc[r]);
                    acc[r] = fmaf(w4[3], h3, acc[r]);
                }
            }
        }

        // ---- split-k reduce ----
        #pragma unroll
        for (int r = 0; r < 8; ++r) part[ks][r][b] = acc[r];
        __syncthreads();                 // sync1: part ready

        // ---- gates -> hlds (tid<128: colL x b) ----
        if (tid < 128) {
            float g4[4];
            #pragma unroll
            for (int g = 0; g < 4; ++g) {
                const int r = g * 2 + colL;
                float v = bias4[g];
                #pragma unroll
                for (int w = 0; w < 4; ++w) v += part[w][r][b];
                g4[g] = v;
            }
            const float si = 1.f / (1.f + expf(-g4[0]));
            const float sf = 1.f / (1.f + expf(-g4[1]));
            const float tg = tanhf(g4[2]);
            const float so = 1.f / (1.f + expf(-g4[3]));
            cst = sf * cst + si * tg;
            hlds[b][colL] = so * tanhf(cst);
        }
        __syncthreads();                 // sync2: hlds ready, part consumed

        // ---- wave0: contiguous sc1 dwordx2 store, drain, publish ----
        if (tid < 64) {
            f32x2 o;
            o[0] = hlds[tid][0]; o[1] = hlds[tid][1];
            float* dst = HH + (((size_t)t * 256 + wg) * 64 + tid) * 2;
            asm volatile("global_store_dwordx2 %0, %1, off sc1"
                         :: "v"(dst), "v"(o) : "memory");
            asm volatile("s_waitcnt vmcnt(0)" ::: "memory");
            if (tid == 0 && s < 511)
                __hip_atomic_fetch_add(
                    ctr + ((size_t)s * 4 + (wg >> 6)) * 16, 1,
                    __ATOMIC_RELAXED, __HIP_MEMORY_SCOPE_AGENT);
        }

        // ---- e-part for step s+1 (in the publish->poll shadow) ----
        if (s < 511) {
            const int tn = dir ? (t - 1) : (t + 1);
            const float4* ep = eg4 + ((size_t)tn * 128 + ks * 32) * 64 + b;
            float4 ev[32];
            #pragma unroll
            for (int kc = 0; kc < 32; ++kc) ev[kc] = ep[(size_t)kc * 64];
            #pragma unroll
            for (int r = 0; r < 8; ++r) eacc[r] = 0.f;
            #pragma unroll
            for (int kc = 0; kc < 32; ++kc) {
                #pragma unroll
                for (int r = 0; r < 8; ++r) {
                    const f32x4 w4 = *reinterpret_cast<const f32x4*>(
                        &wsm[ks][kc * 32 + r * 4]);
                    eacc[r] = fmaf(w4[0], ev[kc].x, eacc[r]);
                    eacc[r] = fmaf(w4[1], ev[kc].y, eacc[r]);
                    eacc[r] = fmaf(w4[2], ev[kc].z, eacc[r]);
                    eacc[r] = fmaf(w4[3], ev[kc].w, eacc[r]);
                }
            }
        }
    }
}

// ---------------------------------------------------------------------------
// K2: emissions  em[t][b][tag] = [hf;hb](t,b,:) . W[tag][:] + bias
// h layout [t][c2][b][2]
// ---------------------------------------------------------------------------
__global__ __launch_bounds__(256) void k_em(
    const float* __restrict__ hf, const float* __restrict__ hb,
    const float* __restrict__ Wm, const float* __restrict__ bias,
    float* __restrict__ em)
{
    const int t   = blockIdx.x;
    const int tid = threadIdx.x;
    const int b   = tid & 63;
    const int tg  = tid >> 6;          // 0..3 -> tags [tg*8, tg*8+8)
    __shared__ float Wl[128][33];
    float acc[8] = {};

    for (int ch = 0; ch < 8; ++ch) {
        {
            const int tag = tid >> 3;   // 0..31
            const int kq  = tid & 7;    // 0..7
            const float* src = Wm + (size_t)tag * 1024 + ch * 128 + kq * 16;
            #pragma unroll
            for (int ii = 0; ii < 4; ++ii) {
                const float4 v = *reinterpret_cast<const float4*>(src + ii * 4);
                const int k0 = kq * 16 + ii * 4;
                Wl[k0 + 0][tag] = v.x; Wl[k0 + 1][tag] = v.y;
                Wl[k0 + 2][tag] = v.z; Wl[k0 + 3][tag] = v.w;
            }
        }
        __syncthreads();
        const f32x2* hsrc2 = (ch < 4)
            ? (reinterpret_cast<const f32x2*>(hf) + ((size_t)t * 256 + ch * 64) * 64 + b)
            : (reinterpret_cast<const f32x2*>(hb) + ((size_t)t * 256 + (ch - 4) * 64) * 64 + b);
        #pragma unroll 4
        for (int c2l = 0; c2l < 64; ++c2l) {
            const f32x2 h2 = hsrc2[(size_t)c2l * 64];
            #pragma unroll
            for (int j = 0; j < 2; ++j)
                #pragma unroll
                for (int jt = 0; jt < 8; ++jt)
                    acc[jt] = fmaf(h2[j], Wl[c2l * 2 + j][tg * 8 + jt], acc[jt]);
        }
        __syncthreads();
    }

    #pragma unroll
    for (int jt = 0; jt < 8; ++jt) {
        const int tag = tg * 8 + jt;
        em[((size_t)t * 64 + b) * 32 + tag] = acc[jt] + bias[tag];
    }
}

// ---------------------------------------------------------------------------
// K3: Viterbi forward + backtrace, one wave per batch row.
// ---------------------------------------------------------------------------
__global__ __launch_bounds__(64) void k_vit(
    const float* __restrict__ em, const float* __restrict__ startv,
    const float* __restrict__ endv, const float* __restrict__ trans,
    int* __restrict__ out)
{
    const int b    = blockIdx.x;
    const int lane = threadIdx.x;
    const int c    = lane & 31;
    const bool act = lane < 32;
    __shared__ unsigned char hist[511][32];
    __shared__ int outb[512];

    float tr[32];
    #pragma unroll 8
    for (int p = 0; p < 32; ++p) tr[p] = trans[p * 32 + c];

    float s = act ? (startv[c] + em[(size_t)b * 32 + c]) : -1e30f;

    for (int t = 1; t < 512; ++t) {
        const float emc = act ? em[((size_t)t * 64 + b) * 32 + c] : 0.f;
        float m = -1e30f; int arg = 0;
        #pragma unroll 8
        for (int p = 0; p < 32; ++p) {
            const float v = __shfl(s, p) + tr[p] + emc;   // (s+tr)+em, ref order
            if (v > m) { m = v; arg = p; }                // strict > => first max
        }
        if (act) { s = m; hist[t - 1][c] = (unsigned char)arg; }
    }

    s = act ? (s + endv[c]) : -1e30f;
    int idx = act ? c : 63;
    #pragma unroll
    for (int off = 32; off >= 1; off >>= 1) {
        const float om = __shfl_down(s, off);
        const int   oi = __shfl_down(idx, off);
        if (om > s || (om == s && oi < idx)) { s = om; idx = oi; }
    }
    idx = __shfl(idx, 0);

    if (lane == 0) {
        int tag = idx;
        outb[511] = tag;
        for (int t = 510; t >= 0; --t) { tag = hist[t][tag]; outb[t] = tag; }
    }
    __syncthreads();
    for (int i = lane; i < 512; i += 64) out[(size_t)b * 512 + i] = outb[i];
}

// ---------------------------------------------------------------------------
extern "C" void kernel_launch(void* const* d_in, const int* in_sizes, int n_in,
                              void* d_out, int out_size, void* d_ws, size_t ws_size,
                              hipStream_t stream)
{
    const int*   x      = (const int*)d_in[0];
    const float* emb    = (const float*)d_in[1];
    const float* w_ih_f = (const float*)d_in[2];
    const float* w_hh_f = (const float*)d_in[3];
    const float* b_f    = (const float*)d_in[4];
    const float* w_ih_b = (const float*)d_in[5];
    const float* w_hh_b = (const float*)d_in[6];
    const float* b_b    = (const float*)d_in[7];
    const float* Wm     = (const float*)d_in[8];
    const float* bvec   = (const float*)d_in[9];
    const float* startv = (const float*)d_in[10];
    const float* endv   = (const float*)d_in[11];
    const float* trans  = (const float*)d_in[12];
    int* out = (int*)d_out;

    float* ws    = (float*)d_ws;
    float* eg    = ws;                          // 16,777,216 f32 (64 MB)
    float* h_f   = ws + 16777216;               // 16,777,216 f32
    float* h_b   = ws + 33554432;               // 16,777,216 f32
    float* em    = ws + 50331648;               //  1,048,576 f32
    float* wpack = ws + 51380224;               //  4,194,304 f32 (16 MB)
    int*   bar   = (int*)(ws + 55574528);       //  65,536 ints (256 KB)

    const size_t need = (size_t)(55574528 + 65536) * 4;
    if (ws_size < need) {
        fprintf(stderr, "kernel_launch: ws too small: %zu < %zu\n", ws_size, need);
        return;
    }

    (void)hipMemsetAsync(bar, 0, 262144, stream);
    k_gather<<<dim3(512),   512, 0, stream>>>(x, emb, (float4*)eg);
    k_pack  <<<dim3(16384), 256, 0, stream>>>(w_ih_f, w_hh_f, w_ih_b, w_hh_b, wpack);
    k_lstm  <<<dim3(512),   256, 0, stream>>>((const float4*)eg, wpack, b_f, b_b,
                                              h_f, h_b, bar);
    k_em    <<<dim3(512),   256, 0, stream>>>(h_f, h_b, Wm, bvec, em);
    k_vit   <<<dim3(64),     64, 0, stream>>>(em, startv, endv, trans, out);
}

// Round 12
// 7344.597 us; speedup vs baseline: 1.2605x; 1.0993x over previous
//
#include <hip/hip_runtime.h>
#include <cstdio>
#include <cstdint>

// V=30000, E=512, H=512, T=32, B=64, L=512
// eg layout: [t][e4:128][b:64][4]   (64 MB)
// h  layout: [t][c4:128][b:64][4]   (64 MB per dir)
// em layout: [t][b][tag]            (4 MB)
// wpack: [dir][wg:128][ks:8][sec:2][kc:16][r:16][j:4]  (16 MB)
// R12 = R8 structure + H-weights resident in LDS (staged once, broadcast
//   ds_read_b128, imm offsets). E-weights stay global: their latency sits in
//   the post-publish shadow. hlds folded into part[7] slots (LDS = 64 KB).
// sync (R10 proven): ctr[dir][step][sub:8] 64B-strided; producer publishes to
//   sub wg>>4 after sc1 store drain; consumer wave ks polls sub ks (==16).

typedef float f32x4 __attribute__((ext_vector_type(4)));

// ---------------------------------------------------------------------------
// K0: embedding gather -> eg[t][e4][b][4]
// ---------------------------------------------------------------------------
__global__ __launch_bounds__(512) void k_gather(
    const int* __restrict__ x, const float* __restrict__ emb,
    float4* __restrict__ eg4)
{
    const int t   = blockIdx.x;
    const int tid = threadIdx.x;
    __shared__ int xv[64];
    if (tid < 64) xv[tid] = x[tid * 512 + t];
    __syncthreads();
    #pragma unroll
    for (int i = 0; i < 16; ++i) {
        const int flat = i * 512 + tid;       // 0..8191
        const int b  = flat & 63;
        const int e4 = flat >> 6;             // 0..127
        const float4 v = *reinterpret_cast<const float4*>(
            emb + (size_t)xv[b] * 512 + e4 * 4);
        eg4[((size_t)t * 128 + e4) * 64 + b] = v;
    }
}

// ---------------------------------------------------------------------------
// K0b: pack weights into per-wave contiguous blocks
// ---------------------------------------------------------------------------
__global__ __launch_bounds__(256) void k_pack(
    const float* __restrict__ wih_f, const float* __restrict__ whh_f,
    const float* __restrict__ wih_b, const float* __restrict__ whh_b,
    float* __restrict__ wpack)
{
    const int i = blockIdx.x * 256 + threadIdx.x;   // 0 .. 4194303
    const int j   = i & 3;
    const int r   = (i >> 2) & 15;
    const int kc  = (i >> 6) & 15;
    const int sec = (i >> 10) & 1;
    const int ks  = (i >> 11) & 7;
    const int wg  = (i >> 14) & 127;
    const int dir = (i >> 21) & 1;
    const int k   = ks * 64 + kc * 4 + j;           // 0..511
    const int g   = r >> 2, cl = r & 3;
    const int rg  = g * 512 + wg * 4 + cl;          // global gate row
    const float* wih = dir ? wih_b : wih_f;
    const float* whh = dir ? whh_b : whh_f;
    const float v = sec ? whh[(size_t)rg * 512 + k] : wih[(size_t)rg * 512 + k];
    wpack[i] = v;
}

// ---------------------------------------------------------------------------
// e-part dot: global weights (shadow path), q = per-lane float4 stream
// ---------------------------------------------------------------------------
__device__ __forceinline__ void dotE(const float4* __restrict__ q,
                                     const float* __restrict__ w,
                                     float acc[16])
{
    float4 v[16];
    #pragma unroll
    for (int kc = 0; kc < 16; ++kc) v[kc] = q[(size_t)kc * 64];
    #pragma unroll
    for (int kc = 0; kc < 16; ++kc) {
        const float* wp = w + kc * 64;
        #pragma unroll
        for (int r = 0; r < 16; ++r) {
            acc[r] = fmaf(wp[r * 4 + 0], v[kc].x, acc[r]);
            acc[r] = fmaf(wp[r * 4 + 1], v[kc].y, acc[r]);
            acc[r] = fmaf(wp[r * 4 + 2], v[kc].z, acc[r]);
            acc[r] = fmaf(wp[r * 4 + 3], v[kc].w, acc[r]);
        }
    }
}

// ---------------------------------------------------------------------------
// K1: persistent BiLSTM recurrence. 256 WGs (128/dir) x 512 threads.
// WG owns 4 h-cols (16 gate rows). lane = b, wave = k-slice (split-k x8).
// H-weights in LDS; E-weights global (shadow). Per-wave dataflow sync.
// ---------------------------------------------------------------------------
__global__ __launch_bounds__(512) void k_lstm(
    const float4* __restrict__ eg4, const float* __restrict__ wpack,
    const float* __restrict__ b_f, const float* __restrict__ b_b,
    float* __restrict__ h_f, float* __restrict__ h_b,
    int* __restrict__ bar)
{
    const int bid = blockIdx.x;
    const int dir = bid >> 7;
    const int wg  = bid & 127;
    float* HH  = dir ? h_b : h_f;
    float4* HH4 = reinterpret_cast<float4*>(HH);
    const float4* HQ = reinterpret_cast<const float4*>(HH);
    const float* BS  = dir ? b_b : b_f;
    int* ctr = bar + (size_t)dir * 512 * 8 * 16;   // [step][sub:8] x 16 ints

    const int tid = threadIdx.x;
    const int b   = tid & 63;
    const int ks  = __builtin_amdgcn_readfirstlane(tid >> 6);

    __shared__ float wlds[8192];        // 32 KB: [ks][kc:16][r:16][j:4] H-weights
    __shared__ float partb[8192];       // 32 KB: [w:8][r:16][b:64]; row [7][col] doubles as hlds

    const float* wbase = wpack + (size_t)((dir * 128 + wg) * 8 + ks) * 2048;
    const float* wE = wbase;            // sec 0 (global, shadow path)

    // ---- stage H-weights (sec 1) into LDS once: 1024 f32 per wave ----
    {
        const float4* src = reinterpret_cast<const float4*>(wbase + 1024);
        float4* dst = reinterpret_cast<float4*>(&wlds[ks * 1024]);
        #pragma unroll
        for (int i = 0; i < 4; ++i)
            dst[i * 64 + b] = src[i * 64 + b];
    }

    const int col = (tid >> 6) & 3;     // gate-phase column (tid<256)
    float bias4[4] = {0.f, 0.f, 0.f, 0.f};
    if (tid < 256) {
        #pragma unroll
        for (int g = 0; g < 4; ++g) bias4[g] = BS[g * 512 + wg * 4 + col];
    }
    float cst = 0.f;

    // prologue: e-part for step 0
    float eacc[16];
    #pragma unroll
    for (int r = 0; r < 16; ++r) eacc[r] = 0.f;
    {
        const int t0 = dir ? 511 : 0;
        dotE(eg4 + ((size_t)t0 * 128 + ks * 16) * 64 + b, wE, eacc);
    }
    __syncthreads();                    // wlds staged

    for (int s = 0; s < 512; ++s) {
        const int t = dir ? (511 - s) : s;
        float acc[16];
        #pragma unroll
        for (int r = 0; r < 16; ++r) acc[r] = eacc[r];

        // ---- per-wave wait on sub ks, then h-dot (LDS weights) ----
        if (s > 0) {
            const int* fp = ctr + ((size_t)(s - 1) * 8 + ks) * 16;
            while (__hip_atomic_load(fp, __ATOMIC_RELAXED,
                                     __HIP_MEMORY_SCOPE_AGENT) < 16)
                __builtin_amdgcn_s_sleep(1);

            const int tp = dir ? (t + 1) : (t - 1);
            const float4* hq = HQ + ((size_t)tp * 128 + ks * 16) * 64 + b;
            float4 v[16];
            #pragma unroll
            for (int kc = 0; kc < 16; ++kc) v[kc] = hq[(size_t)kc * 64];
            const float* wl = &wlds[ks * 1024];
            #pragma unroll
            for (int kc = 0; kc < 16; ++kc) {
                #pragma unroll
                for (int r = 0; r < 16; ++r) {
                    const f32x4 w4 = *reinterpret_cast<const f32x4*>(
                        wl + kc * 64 + r * 4);
                    acc[r] = fmaf(w4[0], v[kc].x, acc[r]);
                    acc[r] = fmaf(w4[1], v[kc].y, acc[r]);
                    acc[r] = fmaf(w4[2], v[kc].z, acc[r]);
                    acc[r] = fmaf(w4[3], v[kc].w, acc[r]);
                }
            }
        }

        // ---- split-k reduce ----
        #pragma unroll
        for (int r = 0; r < 16; ++r) partb[(ks * 16 + r) * 64 + b] = acc[r];
        __syncthreads();                 // sync1: part ready

        // ---- gates; h value goes into part[7][col][b] (own slot) ----
        if (tid < 256) {
            float g4[4];
            #pragma unroll
            for (int g = 0; g < 4; ++g) {
                const int r = g * 4 + col;
                float v = bias4[g];
                #pragma unroll
                for (int w = 0; w < 8; ++w) v += partb[(w * 16 + r) * 64 + b];
                g4[g] = v;
            }
            const float si = 1.f / (1.f + expf(-g4[0]));
            const float sf = 1.f / (1.f + expf(-g4[1]));
            const float tg = tanhf(g4[2]);
            const float so = 1.f / (1.f + expf(-g4[3]));
            cst = sf * cst + si * tg;
            partb[(7 * 16 + col) * 64 + b] = so * tanhf(cst);
        }
        __syncthreads();                 // sync2: h staged, part consumed

        // ---- wave0: coalesced sc1 store, drain, publish to sub wg>>4 ----
        if (tid < 64) {
            f32x4 o;
            o[0] = partb[(7 * 16 + 0) * 64 + tid];
            o[1] = partb[(7 * 16 + 1) * 64 + tid];
            o[2] = partb[(7 * 16 + 2) * 64 + tid];
            o[3] = partb[(7 * 16 + 3) * 64 + tid];
            float4* dst = HH4 + ((size_t)t * 128 + wg) * 64 + tid;
            asm volatile("global_store_dwordx4 %0, %1, off sc1"
                         :: "v"(dst), "v"(o) : "memory");
            asm volatile("s_waitcnt vmcnt(0)" ::: "memory");
            if (tid == 0 && s < 511)
                __hip_atomic_fetch_add(
                    ctr + ((size_t)s * 8 + (wg >> 4)) * 16, 1,
                    __ATOMIC_RELAXED, __HIP_MEMORY_SCOPE_AGENT);
        }

        // ---- e-part for step s+1 (global weights; off critical path) ----
        if (s < 511) {
            const int tn = dir ? (t - 1) : (t + 1);
            #pragma unroll
            for (int r = 0; r < 16; ++r) eacc[r] = 0.f;
            dotE(eg4 + ((size_t)tn * 128 + ks * 16) * 64 + b, wE, eacc);
        }
    }
}

// ---------------------------------------------------------------------------
// K2: emissions  em[t][b][tag] = [hf;hb](t,b,:) . W[tag][:] + bias
// ---------------------------------------------------------------------------
__global__ __launch_bounds__(256) void k_em(
    const float* __restrict__ hf, const float* __restrict__ hb,
    const float* __restrict__ Wm, const float* __restrict__ bias,
    float* __restrict__ em)
{
    const int t   = blockIdx.x;
    const int tid = threadIdx.x;
    const int b   = tid & 63;
    const int tg  = tid >> 6;          // 0..3 -> tags [tg*8, tg*8+8)
    __shared__ float Wl[128][33];
    float acc[8] = {};

    for (int ch = 0; ch < 8; ++ch) {
        {
            const int tag = tid >> 3;   // 0..31
            const int kq  = tid & 7;    // 0..7
            const float* src = Wm + (size_t)tag * 1024 + ch * 128 + kq * 16;
            #pragma unroll
            for (int ii = 0; ii < 4; ++ii) {
                const float4 v = *reinterpret_cast<const float4*>(src + ii * 4);
                const int k0 = kq * 16 + ii * 4;
                Wl[k0 + 0][tag] = v.x; Wl[k0 + 1][tag] = v.y;
                Wl[k0 + 2][tag] = v.z; Wl[k0 + 3][tag] = v.w;
            }
        }
        __syncthreads();
        const float4* hsrc4 = (ch < 4)
            ? (reinterpret_cast<const float4*>(hf) + ((size_t)t * 128 + ch * 32) * 64 + b)
            : (reinterpret_cast<const float4*>(hb) + ((size_t)t * 128 + (ch - 4) * 32) * 64 + b);
        #pragma unroll 4
        for (int c4l = 0; c4l < 32; ++c4l) {
            const float4 h4 = hsrc4[(size_t)c4l * 64];
            const float ha[4] = {h4.x, h4.y, h4.z, h4.w};
            #pragma unroll
            for (int j = 0; j < 4; ++j)
                #pragma unroll
                for (int jt = 0; jt < 8; ++jt)
                    acc[jt] = fmaf(ha[j], Wl[c4l * 4 + j][tg * 8 + jt], acc[jt]);
        }
        __syncthreads();
    }

    #pragma unroll
    for (int jt = 0; jt < 8; ++jt) {
        const int tag = tg * 8 + jt;
        em[((size_t)t * 64 + b) * 32 + tag] = acc[jt] + bias[tag];
    }
}

// ---------------------------------------------------------------------------
// K3: Viterbi forward + backtrace, one wave per batch row.
// ---------------------------------------------------------------------------
__global__ __launch_bounds__(64) void k_vit(
    const float* __restrict__ em, const float* __restrict__ startv,
    const float* __restrict__ endv, const float* __restrict__ trans,
    int* __restrict__ out)
{
    const int b    = blockIdx.x;
    const int lane = threadIdx.x;
    const int c    = lane & 31;
    const bool act = lane < 32;
    __shared__ unsigned char hist[511][32];
    __shared__ int outb[512];

    float tr[32];
    #pragma unroll 8
    for (int p = 0; p < 32; ++p) tr[p] = trans[p * 32 + c];

    float s = act ? (startv[c] + em[(size_t)b * 32 + c]) : -1e30f;

    for (int t = 1; t < 512; ++t) {
        const float emc = act ? em[((size_t)t * 64 + b) * 32 + c] : 0.f;
        float m = -1e30f; int arg = 0;
        #pragma unroll 8
        for (int p = 0; p < 32; ++p) {
            const float v = __shfl(s, p) + tr[p] + emc;   // (s+tr)+em, ref order
            if (v > m) { m = v; arg = p; }                // strict > => first max
        }
        if (act) { s = m; hist[t - 1][c] = (unsigned char)arg; }
    }

    s = act ? (s + endv[c]) : -1e30f;
    int idx = act ? c : 63;
    #pragma unroll
    for (int off = 32; off >= 1; off >>= 1) {
        const float om = __shfl_down(s, off);
        const int   oi = __shfl_down(idx, off);
        if (om > s || (om == s && oi < idx)) { s = om; idx = oi; }
    }
    idx = __shfl(idx, 0);

    if (lane == 0) {
        int tag = idx;
        outb[511] = tag;
        for (int t = 510; t >= 0; --t) { tag = hist[t][tag]; outb[t] = tag; }
    }
    __syncthreads();
    for (int i = lane; i < 512; i += 64) out[(size_t)b * 512 + i] = outb[i];
}

// ---------------------------------------------------------------------------
extern "C" void kernel_launch(void* const* d_in, const int* in_sizes, int n_in,
                              void* d_out, int out_size, void* d_ws, size_t ws_size,
                              hipStream_t stream)
{
    const int*   x      = (const int*)d_in[0];
    const float* emb    = (const float*)d_in[1];
    const float* w_ih_f = (const float*)d_in[2];
    const float* w_hh_f = (const float*)d_in[3];
    const float* b_f    = (const float*)d_in[4];
    const float* w_ih_b = (const float*)d_in[5];
    const float* w_hh_b = (const float*)d_in[6];
    const float* b_b    = (const float*)d_in[7];
    const float* Wm     = (const float*)d_in[8];
    const float* bvec   = (const float*)d_in[9];
    const float* startv = (const float*)d_in[10];
    const float* endv   = (const float*)d_in[11];
    const float* trans  = (const float*)d_in[12];
    int* out = (int*)d_out;

    float* ws    = (float*)d_ws;
    float* eg    = ws;                          // 16,777,216 f32 (64 MB)
    float* h_f   = ws + 16777216;               // 16,777,216 f32
    float* h_b   = ws + 33554432;               // 16,777,216 f32
    float* em    = ws + 50331648;               //  1,048,576 f32
    float* wpack = ws + 51380224;               //  4,194,304 f32 (16 MB)
    int*   bar   = (int*)(ws + 55574528);       //  131,072 ints (512 KB)

    const size_t need = (size_t)(55574528 + 131072) * 4;
    if (ws_size < need) {
        fprintf(stderr, "kernel_launch: ws too small: %zu < %zu\n", ws_size, need);
        return;
    }

    (void)hipMemsetAsync(bar, 0, 524288, stream);
    k_gather<<<dim3(512),   512, 0, stream>>>(x, emb, (float4*)eg);
    k_pack  <<<dim3(16384), 256, 0, stream>>>(w_ih_f, w_hh_f, w_ih_b, w_hh_b, wpack);
    k_lstm  <<<dim3(256),   512, 0, stream>>>((const float4*)eg, wpack, b_f, b_b,
                                              h_f, h_b, bar);
    k_em    <<<dim3(512),   256, 0, stream>>>(h_f, h_b, Wm, bvec, em);
    k_vit   <<<dim3(64),     64, 0, stream>>>(em, startv, endv, trans, out);
}

// Round 13
// 7277.546 us; speedup vs baseline: 1.2721x; 1.0092x over previous
//
#include <hip/hip_runtime.h>
#include <cstdio>
#include <cstdint>

// V=30000, E=512, H=512, T=32, B=64, L=512
// eg layout: [t][e4:128][b:64][4]   (64 MB)
// h  layout: [t][c2:256][b:64][2]   (64 MB per dir)
// em layout: [t][b][tag]            (4 MB)
// wpack: [dir][wg:256][ks:8][sec:2][kc:16][r:8][j:4]  (16 MB)
//   r = gate*2 + colL; global row = gate*512 + wg*2 + colL; k = ks*64+kc*4+j
// R13 = R12 pipeline at 2x finer partition: 512 WGs (256/dir) x 512 thr,
//   2 cols/WG, split-k x8, BOTH weight sections in LDS (32 KB), partb 16 KB.
//   __launch_bounds__(512,4) caps VGPR at 128 -> exactly 2 WGs/CU -> 16
//   waves/CU so co-resident WGs hide each other's sync/miss stalls.
// sync: ctr[dir][step][sub:8] 64B-strided; producer wg publishes to sub
//   wg>>5 after contiguous 512B dwordx2 sc1 store + vmcnt(0) drain;
//   consumer wave ks polls sub ks (its exact 32 producers) until ==32.

typedef float f32x4 __attribute__((ext_vector_type(4)));
typedef float f32x2 __attribute__((ext_vector_type(2)));

// ---------------------------------------------------------------------------
// K0: embedding gather -> eg[t][e4][b][4]
// ---------------------------------------------------------------------------
__global__ __launch_bounds__(512) void k_gather(
    const int* __restrict__ x, const float* __restrict__ emb,
    float4* __restrict__ eg4)
{
    const int t   = blockIdx.x;
    const int tid = threadIdx.x;
    __shared__ int xv[64];
    if (tid < 64) xv[tid] = x[tid * 512 + t];
    __syncthreads();
    #pragma unroll
    for (int i = 0; i < 16; ++i) {
        const int flat = i * 512 + tid;       // 0..8191
        const int b  = flat & 63;
        const int e4 = flat >> 6;             // 0..127
        const float4 v = *reinterpret_cast<const float4*>(
            emb + (size_t)xv[b] * 512 + e4 * 4);
        eg4[((size_t)t * 128 + e4) * 64 + b] = v;
    }
}

// ---------------------------------------------------------------------------
// K0b: pack weights: [dir][wg:256][ks:8][sec:2][kc:16][r:8][j:4]
// ---------------------------------------------------------------------------
__global__ __launch_bounds__(256) void k_pack(
    const float* __restrict__ wih_f, const float* __restrict__ whh_f,
    const float* __restrict__ wih_b, const float* __restrict__ whh_b,
    float* __restrict__ wpack)
{
    const int i = blockIdx.x * 256 + threadIdx.x;   // 0 .. 4194303
    const int j   = i & 3;
    const int r   = (i >> 2) & 7;
    const int kc  = (i >> 5) & 15;
    const int sec = (i >> 9) & 1;
    const int ks  = (i >> 10) & 7;
    const int wg  = (i >> 13) & 255;
    const int dir = (i >> 21) & 1;
    const int k   = ks * 64 + kc * 4 + j;           // 0..511
    const int g   = r >> 1, colL = r & 1;
    const int rg  = g * 512 + wg * 2 + colL;        // global gate row
    const float* wih = dir ? wih_b : wih_f;
    const float* whh = dir ? whh_b : whh_f;
    const float v = sec ? whh[(size_t)rg * 512 + k] : wih[(size_t)rg * 512 + k];
    wpack[i] = v;
}

// ---------------------------------------------------------------------------
// K1: persistent BiLSTM recurrence. 512 WGs (256/dir) x 512 threads.
// WG owns 2 h-cols (8 gate rows). lane = b, wave = k-slice (split-k x8).
// All weights in LDS. Per-wave dataflow sync.
// ---------------------------------------------------------------------------
__global__ __launch_bounds__(512, 4) void k_lstm(
    const float4* __restrict__ eg4, const float* __restrict__ wpack,
    const float* __restrict__ b_f, const float* __restrict__ b_b,
    float* __restrict__ h_f, float* __restrict__ h_b,
    int* __restrict__ bar)
{
    const int bid = blockIdx.x;
    const int dir = bid >> 8;
    const int wg  = bid & 255;
    float* HH       = dir ? h_b : h_f;
    const float* BS = dir ? b_b : b_f;
    int* ctr = bar + (size_t)dir * 65536;   // [step][sub:8] x 16 ints

    const int tid = threadIdx.x;
    const int b   = tid & 63;
    const int ks  = __builtin_amdgcn_readfirstlane(tid >> 6);   // 0..7

    __shared__ float wlds[8][1024];     // 32 KB: per-wave [sec0:512|sec1:512]
    __shared__ float partb[8 * 8 * 64]; // 16 KB split-k exchange
    __shared__ float hlds[64][2];       // h staging for coalesced store

    // ---- stage this wave's weights into LDS once (1024 f32) ----
    {
        const float4* src = reinterpret_cast<const float4*>(
            wpack + (size_t)((dir * 256 + wg) * 8 + ks) * 1024);
        float4* dst = reinterpret_cast<float4*>(&wlds[ks][0]);
        #pragma unroll
        for (int i = 0; i < 4; ++i)
            dst[i * 64 + b] = src[i * 64 + b];
    }

    const int colL = (tid >> 6) & 1;    // gate-phase col (tid<128)
    float bias4[4] = {0.f, 0.f, 0.f, 0.f};
    if (tid < 128) {
        #pragma unroll
        for (int g = 0; g < 4; ++g) bias4[g] = BS[g * 512 + wg * 2 + colL];
    }
    float cst = 0.f;
    __syncthreads();                    // wlds ready

    const float* wl = &wlds[ks][0];

    // prologue: e-part for step 0 (LDS weights)
    float eacc[8];
    #pragma unroll
    for (int r = 0; r < 8; ++r) eacc[r] = 0.f;
    {
        const int t0 = dir ? 511 : 0;
        const float4* ep = eg4 + ((size_t)t0 * 128 + ks * 16) * 64 + b;
        #pragma unroll
        for (int half = 0; half < 2; ++half) {
            float4 v[8];
            #pragma unroll
            for (int kc = 0; kc < 8; ++kc)
                v[kc] = ep[(size_t)(half * 8 + kc) * 64];
            #pragma unroll
            for (int kc = 0; kc < 8; ++kc) {
                const float* wp = wl + (half * 8 + kc) * 32;
                #pragma unroll
                for (int r = 0; r < 8; ++r) {
                    const f32x4 w4 = *reinterpret_cast<const f32x4*>(wp + r * 4);
                    eacc[r] = fmaf(w4[0], v[kc].x, eacc[r]);
                    eacc[r] = fmaf(w4[1], v[kc].y, eacc[r]);
                    eacc[r] = fmaf(w4[2], v[kc].z, eacc[r]);
                    eacc[r] = fmaf(w4[3], v[kc].w, eacc[r]);
                }
            }
        }
    }

    for (int s = 0; s < 512; ++s) {
        const int t = dir ? (511 - s) : s;
        float acc[8];
        #pragma unroll
        for (int r = 0; r < 8; ++r) acc[r] = eacc[r];

        // ---- per-wave wait on sub ks, then h-dot (LDS weights) ----
        if (s > 0) {
            const int* fp = ctr + ((size_t)(s - 1) * 8 + ks) * 16;
            while (__hip_atomic_load(fp, __ATOMIC_RELAXED,
                                     __HIP_MEMORY_SCOPE_AGENT) < 32)
                __builtin_amdgcn_s_sleep(1);

            const int tp = dir ? (t + 1) : (t - 1);
            const f32x2* hq = reinterpret_cast<const f32x2*>(HH)
                              + ((size_t)tp * 256 + ks * 32) * 64 + b;
            #pragma unroll
            for (int half = 0; half < 2; ++half) {
                f32x2 hv[16];
                #pragma unroll
                for (int kq = 0; kq < 16; ++kq)
                    hv[kq] = hq[(size_t)(half * 16 + kq) * 64];
                #pragma unroll
                for (int kc = 0; kc < 8; ++kc) {
                    const float* wp = wl + 512 + (half * 8 + kc) * 32;
                    const float h0 = hv[kc * 2][0],     h1 = hv[kc * 2][1];
                    const float h2 = hv[kc * 2 + 1][0], h3 = hv[kc * 2 + 1][1];
                    #pragma unroll
                    for (int r = 0; r < 8; ++r) {
                        const f32x4 w4 = *reinterpret_cast<const f32x4*>(wp + r * 4);
                        acc[r] = fmaf(w4[0], h0, acc[r]);
                        acc[r] = fmaf(w4[1], h1, acc[r]);
                        acc[r] = fmaf(w4[2], h2, acc[r]);
                        acc[r] = fmaf(w4[3], h3, acc[r]);
                    }
                }
            }
        }

        // ---- split-k reduce ----
        #pragma unroll
        for (int r = 0; r < 8; ++r) partb[(ks * 8 + r) * 64 + b] = acc[r];
        __syncthreads();                 // sync1: part ready

        // ---- gates (tid<128: colL x b) ----
        if (tid < 128) {
            float g4[4];
            #pragma unroll
            for (int g = 0; g < 4; ++g) {
                const int r = g * 2 + colL;
                float v = bias4[g];
                #pragma unroll
                for (int w = 0; w < 8; ++w) v += partb[(w * 8 + r) * 64 + b];
                g4[g] = v;
            }
            const float si = 1.f / (1.f + expf(-g4[0]));
            const float sf = 1.f / (1.f + expf(-g4[1]));
            const float tg = tanhf(g4[2]);
            const float so = 1.f / (1.f + expf(-g4[3]));
            cst = sf * cst + si * tg;
            hlds[b][colL] = so * tanhf(cst);
        }
        __syncthreads();                 // sync2: hlds ready, part consumed

        // ---- wave0: contiguous sc1 dwordx2 store, drain, publish ----
        if (tid < 64) {
            f32x2 o;
            o[0] = hlds[tid][0]; o[1] = hlds[tid][1];
            float* dst = HH + (((size_t)t * 256 + wg) * 64 + tid) * 2;
            asm volatile("global_store_dwordx2 %0, %1, off sc1"
                         :: "v"(dst), "v"(o) : "memory");
            asm volatile("s_waitcnt vmcnt(0)" ::: "memory");
            if (tid == 0 && s < 511)
                __hip_atomic_fetch_add(
                    ctr + ((size_t)s * 8 + (wg >> 5)) * 16, 1,
                    __ATOMIC_RELAXED, __HIP_MEMORY_SCOPE_AGENT);
        }

        // ---- e-part for step s+1 (LDS weights; off critical path) ----
        if (s < 511) {
            const int tn = dir ? (t - 1) : (t + 1);
            const float4* ep = eg4 + ((size_t)tn * 128 + ks * 16) * 64 + b;
            #pragma unroll
            for (int r = 0; r < 8; ++r) eacc[r] = 0.f;
            #pragma unroll
            for (int half = 0; half < 2; ++half) {
                float4 v[8];
                #pragma unroll
                for (int kc = 0; kc < 8; ++kc)
                    v[kc] = ep[(size_t)(half * 8 + kc) * 64];
                #pragma unroll
                for (int kc = 0; kc < 8; ++kc) {
                    const float* wp = wl + (half * 8 + kc) * 32;
                    #pragma unroll
                    for (int r = 0; r < 8; ++r) {
                        const f32x4 w4 = *reinterpret_cast<const f32x4*>(wp + r * 4);
                        eacc[r] = fmaf(w4[0], v[kc].x, eacc[r]);
                        eacc[r] = fmaf(w4[1], v[kc].y, eacc[r]);
                        eacc[r] = fmaf(w4[2], v[kc].z, eacc[r]);
                        eacc[r] = fmaf(w4[3], v[kc].w, eacc[r]);
                    }
                }
            }
        }
    }
}

// ---------------------------------------------------------------------------
// K2: emissions  em[t][b][tag] = [hf;hb](t,b,:) . W[tag][:] + bias
// h layout [t][c2][b][2]
// ---------------------------------------------------------------------------
__global__ __launch_bounds__(256) void k_em(
    const float* __restrict__ hf, const float* __restrict__ hb,
    const float* __restrict__ Wm, const float* __restrict__ bias,
    float* __restrict__ em)
{
    const int t   = blockIdx.x;
    const int tid = threadIdx.x;
    const int b   = tid & 63;
    const int tg  = tid >> 6;          // 0..3 -> tags [tg*8, tg*8+8)
    __shared__ float Wl[128][33];
    float acc[8] = {};

    for (int ch = 0; ch < 8; ++ch) {
        {
            const int tag = tid >> 3;   // 0..31
            const int kq  = tid & 7;    // 0..7
            const float* src = Wm + (size_t)tag * 1024 + ch * 128 + kq * 16;
            #pragma unroll
            for (int ii = 0; ii < 4; ++ii) {
                const float4 v = *reinterpret_cast<const float4*>(src + ii * 4);
                const int k0 = kq * 16 + ii * 4;
                Wl[k0 + 0][tag] = v.x; Wl[k0 + 1][tag] = v.y;
                Wl[k0 + 2][tag] = v.z; Wl[k0 + 3][tag] = v.w;
            }
        }
        __syncthreads();
        const f32x2* hsrc2 = (ch < 4)
            ? (reinterpret_cast<const f32x2*>(hf) + ((size_t)t * 256 + ch * 64) * 64 + b)
            : (reinterpret_cast<const f32x2*>(hb) + ((size_t)t * 256 + (ch - 4) * 64) * 64 + b);
        #pragma unroll 4
        for (int c2l = 0; c2l < 64; ++c2l) {
            const f32x2 h2 = hsrc2[(size_t)c2l * 64];
            #pragma unroll
            for (int j = 0; j < 2; ++j)
                #pragma unroll
                for (int jt = 0; jt < 8; ++jt)
                    acc[jt] = fmaf(h2[j], Wl[c2l * 2 + j][tg * 8 + jt], acc[jt]);
        }
        __syncthreads();
    }

    #pragma unroll
    for (int jt = 0; jt < 8; ++jt) {
        const int tag = tg * 8 + jt;
        em[((size_t)t * 64 + b) * 32 + tag] = acc[jt] + bias[tag];
    }
}

// ---------------------------------------------------------------------------
// K3: Viterbi forward + backtrace, one wave per batch row.
// ---------------------------------------------------------------------------
__global__ __launch_bounds__(64) void k_vit(
    const float* __restrict__ em, const float* __restrict__ startv,
    const float* __restrict__ endv, const float* __restrict__ trans,
    int* __restrict__ out)
{
    const int b    = blockIdx.x;
    const int lane = threadIdx.x;
    const int c    = lane & 31;
    const bool act = lane < 32;
    __shared__ unsigned char hist[511][32];
    __shared__ int outb[512];

    float tr[32];
    #pragma unroll 8
    for (int p = 0; p < 32; ++p) tr[p] = trans[p * 32 + c];

    float s = act ? (startv[c] + em[(size_t)b * 32 + c]) : -1e30f;

    for (int t = 1; t < 512; ++t) {
        const float emc = act ? em[((size_t)t * 64 + b) * 32 + c] : 0.f;
        float m = -1e30f; int arg = 0;
        #pragma unroll 8
        for (int p = 0; p < 32; ++p) {
            const float v = __shfl(s, p) + tr[p] + emc;   // (s+tr)+em, ref order
            if (v > m) { m = v; arg = p; }                // strict > => first max
        }
        if (act) { s = m; hist[t - 1][c] = (unsigned char)arg; }
    }

    s = act ? (s + endv[c]) : -1e30f;
    int idx = act ? c : 63;
    #pragma unroll
    for (int off = 32; off >= 1; off >>= 1) {
        const float om = __shfl_down(s, off);
        const int   oi = __shfl_down(idx, off);
        if (om > s || (om == s && oi < idx)) { s = om; idx = oi; }
    }
    idx = __shfl(idx, 0);

    if (lane == 0) {
        int tag = idx;
        outb[511] = tag;
        for (int t = 510; t >= 0; --t) { tag = hist[t][tag]; outb[t] = tag; }
    }
    __syncthreads();
    for (int i = lane; i < 512; i += 64) out[(size_t)b * 512 + i] = outb[i];
}

// ---------------------------------------------------------------------------
extern "C" void kernel_launch(void* const* d_in, const int* in_sizes, int n_in,
                              void* d_out, int out_size, void* d_ws, size_t ws_size,
                              hipStream_t stream)
{
    const int*   x      = (const int*)d_in[0];
    const float* emb    = (const float*)d_in[1];
    const float* w_ih_f = (const float*)d_in[2];
    const float* w_hh_f = (const float*)d_in[3];
    const float* b_f    = (const float*)d_in[4];
    const float* w_ih_b = (const float*)d_in[5];
    const float* w_hh_b = (const float*)d_in[6];
    const float* b_b    = (const float*)d_in[7];
    const float* Wm     = (const float*)d_in[8];
    const float* bvec   = (const float*)d_in[9];
    const float* startv = (const float*)d_in[10];
    const float* endv   = (const float*)d_in[11];
    const float* trans  = (const float*)d_in[12];
    int* out = (int*)d_out;

    float* ws    = (float*)d_ws;
    float* eg    = ws;                          // 16,777,216 f32 (64 MB)
    float* h_f   = ws + 16777216;               // 16,777,216 f32
    float* h_b   = ws + 33554432;               // 16,777,216 f32
    float* em    = ws + 50331648;               //  1,048,576 f32
    float* wpack = ws + 51380224;               //  4,194,304 f32 (16 MB)
    int*   bar   = (int*)(ws + 55574528);       //  131,072 ints (512 KB)

    const size_t need = (size_t)(55574528 + 131072) * 4;
    if (ws_size < need) {
        fprintf(stderr, "kernel_launch: ws too small: %zu < %zu\n", ws_size, need);
        return;
    }

    (void)hipMemsetAsync(bar, 0, 524288, stream);
    k_gather<<<dim3(512),   512, 0, stream>>>(x, emb, (float4*)eg);
    k_pack  <<<dim3(16384), 256, 0, stream>>>(w_ih_f, w_hh_f, w_ih_b, w_hh_b, wpack);
    k_lstm  <<<dim3(512),   512, 0, stream>>>((const float4*)eg, wpack, b_f, b_b,
                                              h_f, h_b, bar);
    k_em    <<<dim3(512),   256, 0, stream>>>(h_f, h_b, Wm, bvec, em);
    k_vit   <<<dim3(64),     64, 0, stream>>>(em, startv, endv, trans, out);
}

// Round 14
// 7256.420 us; speedup vs baseline: 1.2758x; 1.0029x over previous
//
#include <hip/hip_runtime.h>
#include <cstdio>
#include <cstdint>

// V=30000, E=512, H=512, T=32, B=64, L=512
// eg layout: [t][e4:128][b:64][4]   (64 MB)
// h  layout: [t][c2:256][b:64][2]   (64 MB per dir)
// em layout: [t][b][tag]            (4 MB)
// wpack: [dir][wg:256][ks:8][sec:2][kc:16][r:8][j:4]  (16 MB)
// R14 = R13 with __launch_bounds__(512,2): R13's (512,4) made the allocator
//   squeeze to 64 VGPRs -> ~3.3x VALU instruction bloat (remat/reissue).
//   Target ~100-120 VGPRs (<=128 keeps 2 WGs/CU); h operands staged as one
//   hv[32] batch for deeper load pipelining.
// sync: ctr[dir][step][sub:8] 64B-strided; producer wg publishes to sub
//   wg>>5 after contiguous 512B dwordx2 sc1 store + vmcnt(0) drain;
//   consumer wave ks polls sub ks (its exact 32 producers) until ==32.

typedef float f32x4 __attribute__((ext_vector_type(4)));
typedef float f32x2 __attribute__((ext_vector_type(2)));

// ---------------------------------------------------------------------------
// K0: embedding gather -> eg[t][e4][b][4]
// ---------------------------------------------------------------------------
__global__ __launch_bounds__(512) void k_gather(
    const int* __restrict__ x, const float* __restrict__ emb,
    float4* __restrict__ eg4)
{
    const int t   = blockIdx.x;
    const int tid = threadIdx.x;
    __shared__ int xv[64];
    if (tid < 64) xv[tid] = x[tid * 512 + t];
    __syncthreads();
    #pragma unroll
    for (int i = 0; i < 16; ++i) {
        const int flat = i * 512 + tid;       // 0..8191
        const int b  = flat & 63;
        const int e4 = flat >> 6;             // 0..127
        const float4 v = *reinterpret_cast<const float4*>(
            emb + (size_t)xv[b] * 512 + e4 * 4);
        eg4[((size_t)t * 128 + e4) * 64 + b] = v;
    }
}

// ---------------------------------------------------------------------------
// K0b: pack weights: [dir][wg:256][ks:8][sec:2][kc:16][r:8][j:4]
// ---------------------------------------------------------------------------
__global__ __launch_bounds__(256) void k_pack(
    const float* __restrict__ wih_f, const float* __restrict__ whh_f,
    const float* __restrict__ wih_b, const float* __restrict__ whh_b,
    float* __restrict__ wpack)
{
    const int i = blockIdx.x * 256 + threadIdx.x;   // 0 .. 4194303
    const int j   = i & 3;
    const int r   = (i >> 2) & 7;
    const int kc  = (i >> 5) & 15;
    const int sec = (i >> 9) & 1;
    const int ks  = (i >> 10) & 7;
    const int wg  = (i >> 13) & 255;
    const int dir = (i >> 21) & 1;
    const int k   = ks * 64 + kc * 4 + j;           // 0..511
    const int g   = r >> 1, colL = r & 1;
    const int rg  = g * 512 + wg * 2 + colL;        // global gate row
    const float* wih = dir ? wih_b : wih_f;
    const float* whh = dir ? whh_b : whh_f;
    const float v = sec ? whh[(size_t)rg * 512 + k] : wih[(size_t)rg * 512 + k];
    wpack[i] = v;
}

// ---------------------------------------------------------------------------
// K1: persistent BiLSTM recurrence. 512 WGs (256/dir) x 512 threads.
// WG owns 2 h-cols (8 gate rows). lane = b, wave = k-slice (split-k x8).
// All weights in LDS. Per-wave dataflow sync.
// ---------------------------------------------------------------------------
__global__ __launch_bounds__(512, 2) void k_lstm(
    const float4* __restrict__ eg4, const float* __restrict__ wpack,
    const float* __restrict__ b_f, const float* __restrict__ b_b,
    float* __restrict__ h_f, float* __restrict__ h_b,
    int* __restrict__ bar)
{
    const int bid = blockIdx.x;
    const int dir = bid >> 8;
    const int wg  = bid & 255;
    float* HH       = dir ? h_b : h_f;
    const float* BS = dir ? b_b : b_f;
    int* ctr = bar + (size_t)dir * 65536;   // [step][sub:8] x 16 ints

    const int tid = threadIdx.x;
    const int b   = tid & 63;
    const int ks  = __builtin_amdgcn_readfirstlane(tid >> 6);   // 0..7

    __shared__ float wlds[8][1024];     // 32 KB: per-wave [sec0:512|sec1:512]
    __shared__ float partb[8 * 8 * 64]; // 16 KB split-k exchange
    __shared__ float hlds[64][2];       // h staging for coalesced store

    // ---- stage this wave's weights into LDS once (1024 f32) ----
    {
        const float4* src = reinterpret_cast<const float4*>(
            wpack + (size_t)((dir * 256 + wg) * 8 + ks) * 1024);
        float4* dst = reinterpret_cast<float4*>(&wlds[ks][0]);
        #pragma unroll
        for (int i = 0; i < 4; ++i)
            dst[i * 64 + b] = src[i * 64 + b];
    }

    const int colL = (tid >> 6) & 1;    // gate-phase col (tid<128)
    float bias4[4] = {0.f, 0.f, 0.f, 0.f};
    if (tid < 128) {
        #pragma unroll
        for (int g = 0; g < 4; ++g) bias4[g] = BS[g * 512 + wg * 2 + colL];
    }
    float cst = 0.f;
    __syncthreads();                    // wlds ready

    const float* wl = &wlds[ks][0];

    // prologue: e-part for step 0 (LDS weights)
    float eacc[8];
    #pragma unroll
    for (int r = 0; r < 8; ++r) eacc[r] = 0.f;
    {
        const int t0 = dir ? 511 : 0;
        const float4* ep = eg4 + ((size_t)t0 * 128 + ks * 16) * 64 + b;
        float4 v[16];
        #pragma unroll
        for (int kc = 0; kc < 16; ++kc)
            v[kc] = ep[(size_t)kc * 64];
        #pragma unroll
        for (int kc = 0; kc < 16; ++kc) {
            const float* wp = wl + kc * 32;
            #pragma unroll
            for (int r = 0; r < 8; ++r) {
                const f32x4 w4 = *reinterpret_cast<const f32x4*>(wp + r * 4);
                eacc[r] = fmaf(w4[0], v[kc].x, eacc[r]);
                eacc[r] = fmaf(w4[1], v[kc].y, eacc[r]);
                eacc[r] = fmaf(w4[2], v[kc].z, eacc[r]);
                eacc[r] = fmaf(w4[3], v[kc].w, eacc[r]);
            }
        }
    }

    for (int s = 0; s < 512; ++s) {
        const int t = dir ? (511 - s) : s;
        float acc[8];
        #pragma unroll
        for (int r = 0; r < 8; ++r) acc[r] = eacc[r];

        // ---- per-wave wait on sub ks, then h-dot (LDS weights) ----
        if (s > 0) {
            const int* fp = ctr + ((size_t)(s - 1) * 8 + ks) * 16;
            while (__hip_atomic_load(fp, __ATOMIC_RELAXED,
                                     __HIP_MEMORY_SCOPE_AGENT) < 32)
                __builtin_amdgcn_s_sleep(1);

            const int tp = dir ? (t + 1) : (t - 1);
            const f32x2* hq = reinterpret_cast<const f32x2*>(HH)
                              + ((size_t)tp * 256 + ks * 32) * 64 + b;
            f32x2 hv[32];
            #pragma unroll
            for (int kq = 0; kq < 32; ++kq)
                hv[kq] = hq[(size_t)kq * 64];
            #pragma unroll
            for (int kc = 0; kc < 16; ++kc) {
                const float* wp = wl + 512 + kc * 32;
                const float h0 = hv[kc * 2][0],     h1 = hv[kc * 2][1];
                const float h2 = hv[kc * 2 + 1][0], h3 = hv[kc * 2 + 1][1];
                #pragma unroll
                for (int r = 0; r < 8; ++r) {
                    const f32x4 w4 = *reinterpret_cast<const f32x4*>(wp + r * 4);
                    acc[r] = fmaf(w4[0], h0, acc[r]);
                    acc[r] = fmaf(w4[1], h1, acc[r]);
                    acc[r] = fmaf(w4[2], h2, acc[r]);
                    acc[r] = fmaf(w4[3], h3, acc[r]);
                }
            }
        }

        // ---- split-k reduce ----
        #pragma unroll
        for (int r = 0; r < 8; ++r) partb[(ks * 8 + r) * 64 + b] = acc[r];
        __syncthreads();                 // sync1: part ready

        // ---- gates (tid<128: colL x b) ----
        if (tid < 128) {
            float g4[4];
            #pragma unroll
            for (int g = 0; g < 4; ++g) {
                const int r = g * 2 + colL;
                float v = bias4[g];
                #pragma unroll
                for (int w = 0; w < 8; ++w) v += partb[(w * 8 + r) * 64 + b];
                g4[g] = v;
            }
            const float si = 1.f / (1.f + expf(-g4[0]));
            const float sf = 1.f / (1.f + expf(-g4[1]));
            const float tg = tanhf(g4[2]);
            const float so = 1.f / (1.f + expf(-g4[3]));
            cst = sf * cst + si * tg;
            hlds[b][colL] = so * tanhf(cst);
        }
        __syncthreads();                 // sync2: hlds ready, part consumed

        // ---- wave0: contiguous sc1 dwordx2 store, drain, publish ----
        if (tid < 64) {
            f32x2 o;
            o[0] = hlds[tid][0]; o[1] = hlds[tid][1];
            float* dst = HH + (((size_t)t * 256 + wg) * 64 + tid) * 2;
            asm volatile("global_store_dwordx2 %0, %1, off sc1"
                         :: "v"(dst), "v"(o) : "memory");
            asm volatile("s_waitcnt vmcnt(0)" ::: "memory");
            if (tid == 0 && s < 511)
                __hip_atomic_fetch_add(
                    ctr + ((size_t)s * 8 + (wg >> 5)) * 16, 1,
                    __ATOMIC_RELAXED, __HIP_MEMORY_SCOPE_AGENT);
        }

        // ---- e-part for step s+1 (LDS weights; off critical path) ----
        if (s < 511) {
            const int tn = dir ? (t - 1) : (t + 1);
            const float4* ep = eg4 + ((size_t)tn * 128 + ks * 16) * 64 + b;
            float4 v[16];
            #pragma unroll
            for (int kc = 0; kc < 16; ++kc)
                v[kc] = ep[(size_t)kc * 64];
            #pragma unroll
            for (int r = 0; r < 8; ++r) eacc[r] = 0.f;
            #pragma unroll
            for (int kc = 0; kc < 16; ++kc) {
                const float* wp = wl + kc * 32;
                #pragma unroll
                for (int r = 0; r < 8; ++r) {
                    const f32x4 w4 = *reinterpret_cast<const f32x4*>(wp + r * 4);
                    eacc[r] = fmaf(w4[0], v[kc].x, eacc[r]);
                    eacc[r] = fmaf(w4[1], v[kc].y, eacc[r]);
                    eacc[r] = fmaf(w4[2], v[kc].z, eacc[r]);
                    eacc[r] = fmaf(w4[3], v[kc].w, eacc[r]);
                }
            }
        }
    }
}

// ---------------------------------------------------------------------------
// K2: emissions  em[t][b][tag] = [hf;hb](t,b,:) . W[tag][:] + bias
// h layout [t][c2][b][2]
// ---------------------------------------------------------------------------
__global__ __launch_bounds__(256) void k_em(
    const float* __restrict__ hf, const float* __restrict__ hb,
    const float* __restrict__ Wm, const float* __restrict__ bias,
    float* __restrict__ em)
{
    const int t   = blockIdx.x;
    const int tid = threadIdx.x;
    const int b   = tid & 63;
    const int tg  = tid >> 6;          // 0..3 -> tags [tg*8, tg*8+8)
    __shared__ float Wl[128][33];
    float acc[8] = {};

    for (int ch = 0; ch < 8; ++ch) {
        {
            const int tag = tid >> 3;   // 0..31
            const int kq  = tid & 7;    // 0..7
            const float* src = Wm + (size_t)tag * 1024 + ch * 128 + kq * 16;
            #pragma unroll
            for (int ii = 0; ii < 4; ++ii) {
                const float4 v = *reinterpret_cast<const float4*>(src + ii * 4);
                const int k0 = kq * 16 + ii * 4;
                Wl[k0 + 0][tag] = v.x; Wl[k0 + 1][tag] = v.y;
                Wl[k0 + 2][tag] = v.z; Wl[k0 + 3][tag] = v.w;
            }
        }
        __syncthreads();
        const f32x2* hsrc2 = (ch < 4)
            ? (reinterpret_cast<const f32x2*>(hf) + ((size_t)t * 256 + ch * 64) * 64 + b)
            : (reinterpret_cast<const f32x2*>(hb) + ((size_t)t * 256 + (ch - 4) * 64) * 64 + b);
        #pragma unroll 4
        for (int c2l = 0; c2l < 64; ++c2l) {
            const f32x2 h2 = hsrc2[(size_t)c2l * 64];
            #pragma unroll
            for (int j = 0; j < 2; ++j)
                #pragma unroll
                for (int jt = 0; jt < 8; ++jt)
                    acc[jt] = fmaf(h2[j], Wl[c2l * 2 + j][tg * 8 + jt], acc[jt]);
        }
        __syncthreads();
    }

    #pragma unroll
    for (int jt = 0; jt < 8; ++jt) {
        const int tag = tg * 8 + jt;
        em[((size_t)t * 64 + b) * 32 + tag] = acc[jt] + bias[tag];
    }
}

// ---------------------------------------------------------------------------
// K3: Viterbi forward + backtrace, one wave per batch row.
// ---------------------------------------------------------------------------
__global__ __launch_bounds__(64) void k_vit(
    const float* __restrict__ em, const float* __restrict__ startv,
    const float* __restrict__ endv, const float* __restrict__ trans,
    int* __restrict__ out)
{
    const int b    = blockIdx.x;
    const int lane = threadIdx.x;
    const int c    = lane & 31;
    const bool act = lane < 32;
    __shared__ unsigned char hist[511][32];
    __shared__ int outb[512];

    float tr[32];
    #pragma unroll 8
    for (int p = 0; p < 32; ++p) tr[p] = trans[p * 32 + c];

    float s = act ? (startv[c] + em[(size_t)b * 32 + c]) : -1e30f;

    for (int t = 1; t < 512; ++t) {
        const float emc = act ? em[((size_t)t * 64 + b) * 32 + c] : 0.f;
        float m = -1e30f; int arg = 0;
        #pragma unroll 8
        for (int p = 0; p < 32; ++p) {
            const float v = __shfl(s, p) + tr[p] + emc;   // (s+tr)+em, ref order
            if (v > m) { m = v; arg = p; }                // strict > => first max
        }
        if (act) { s = m; hist[t - 1][c] = (unsigned char)arg; }
    }

    s = act ? (s + endv[c]) : -1e30f;
    int idx = act ? c : 63;
    #pragma unroll
    for (int off = 32; off >= 1; off >>= 1) {
        const float om = __shfl_down(s, off);
        const int   oi = __shfl_down(idx, off);
        if (om > s || (om == s && oi < idx)) { s = om; idx = oi; }
    }
    idx = __shfl(idx, 0);

    if (lane == 0) {
        int tag = idx;
        outb[511] = tag;
        for (int t = 510; t >= 0; --t) { tag = hist[t][tag]; outb[t] = tag; }
    }
    __syncthreads();
    for (int i = lane; i < 512; i += 64) out[(size_t)b * 512 + i] = outb[i];
}

// ---------------------------------------------------------------------------
extern "C" void kernel_launch(void* const* d_in, const int* in_sizes, int n_in,
                              void* d_out, int out_size, void* d_ws, size_t ws_size,
                              hipStream_t stream)
{
    const int*   x      = (const int*)d_in[0];
    const float* emb    = (const float*)d_in[1];
    const float* w_ih_f = (const float*)d_in[2];
    const float* w_hh_f = (const float*)d_in[3];
    const float* b_f    = (const float*)d_in[4];
    const float* w_ih_b = (const float*)d_in[5];
    const float* w_hh_b = (const float*)d_in[6];
    const float* b_b    = (const float*)d_in[7];
    const float* Wm     = (const float*)d_in[8];
    const float* bvec   = (const float*)d_in[9];
    const float* startv = (const float*)d_in[10];
    const float* endv   = (const float*)d_in[11];
    const float* trans  = (const float*)d_in[12];
    int* out = (int*)d_out;

    float* ws    = (float*)d_ws;
    float* eg    = ws;                          // 16,777,216 f32 (64 MB)
    float* h_f   = ws + 16777216;               // 16,777,216 f32
    float* h_b   = ws + 33554432;               // 16,777,216 f32
    float* em    = ws + 50331648;               //  1,048,576 f32
    float* wpack = ws + 51380224;               //  4,194,304 f32 (16 MB)
    int*   bar   = (int*)(ws + 55574528);       //  131,072 ints (512 KB)

    const size_t need = (size_t)(55574528 + 131072) * 4;
    if (ws_size < need) {
        fprintf(stderr, "kernel_launch: ws too small: %zu < %zu\n", ws_size, need);
        return;
    }

    (void)hipMemsetAsync(bar, 0, 524288, stream);
    k_gather<<<dim3(512),   512, 0, stream>>>(x, emb, (float4*)eg);
    k_pack  <<<dim3(16384), 256, 0, stream>>>(w_ih_f, w_hh_f, w_ih_b, w_hh_b, wpack);
    k_lstm  <<<dim3(512),   512, 0, stream>>>((const float4*)eg, wpack, b_f, b_b,
                                              h_f, h_b, bar);
    k_em    <<<dim3(512),   256, 0, stream>>>(h_f, h_b, Wm, bvec, em);
    k_vit   <<<dim3(64),     64, 0, stream>>>(em, startv, endv, trans, out);
}

// Round 15
// 6382.299 us; speedup vs baseline: 1.4506x; 1.1370x over previous
//
#include <hip/hip_runtime.h>
#include <cstdio>
#include <cstdint>

// V=30000, E=512, H=512, T=32, B=64, L=512
// eg layout: [t][e4:128][b:64][4]   (64 MB)
// h  layout: [t][c2:256][b:64][2]   (64 MB per dir)
// em layout: [t][b][tag]            (4 MB)
// wpack: [dir][wg:256][ks:8][sec:2][kc:16][r:8][j:4]  (16 MB)
// R15 = R13 structure + v_pk_fma_f32 (VOP3P packed f32, 2 FMA/instr) on both
//   dot sections. k-pairs are native: hv[kq] f32x2 = (k=2kq,2kq+1); weight
//   b128 reads split into exact f32x2 subregister halves. Accumulators are
//   packed (even-k lo, odd-k hi), one horizontal add per row per step.
// sync: ctr[dir][step][sub:8] 64B-strided; producer wg publishes to sub
//   wg>>5 after contiguous 512B dwordx2 sc1 store + vmcnt(0) drain;
//   consumer wave ks polls sub ks (its exact 32 producers) until ==32.

typedef float f32x4 __attribute__((ext_vector_type(4)));
typedef float f32x2 __attribute__((ext_vector_type(2)));

#define PKFMA(ACC, W2, H2) \
    asm("v_pk_fma_f32 %0, %1, %2, %0" : "+v"(ACC) : "v"(W2), "v"(H2))

// ---------------------------------------------------------------------------
// K0: embedding gather -> eg[t][e4][b][4]
// ---------------------------------------------------------------------------
__global__ __launch_bounds__(512) void k_gather(
    const int* __restrict__ x, const float* __restrict__ emb,
    float4* __restrict__ eg4)
{
    const int t   = blockIdx.x;
    const int tid = threadIdx.x;
    __shared__ int xv[64];
    if (tid < 64) xv[tid] = x[tid * 512 + t];
    __syncthreads();
    #pragma unroll
    for (int i = 0; i < 16; ++i) {
        const int flat = i * 512 + tid;       // 0..8191
        const int b  = flat & 63;
        const int e4 = flat >> 6;             // 0..127
        const float4 v = *reinterpret_cast<const float4*>(
            emb + (size_t)xv[b] * 512 + e4 * 4);
        eg4[((size_t)t * 128 + e4) * 64 + b] = v;
    }
}

// ---------------------------------------------------------------------------
// K0b: pack weights: [dir][wg:256][ks:8][sec:2][kc:16][r:8][j:4]
// ---------------------------------------------------------------------------
__global__ __launch_bounds__(256) void k_pack(
    const float* __restrict__ wih_f, const float* __restrict__ whh_f,
    const float* __restrict__ wih_b, const float* __restrict__ whh_b,
    float* __restrict__ wpack)
{
    const int i = blockIdx.x * 256 + threadIdx.x;   // 0 .. 4194303
    const int j   = i & 3;
    const int r   = (i >> 2) & 7;
    const int kc  = (i >> 5) & 15;
    const int sec = (i >> 9) & 1;
    const int ks  = (i >> 10) & 7;
    const int wg  = (i >> 13) & 255;
    const int dir = (i >> 21) & 1;
    const int k   = ks * 64 + kc * 4 + j;           // 0..511
    const int g   = r >> 1, colL = r & 1;
    const int rg  = g * 512 + wg * 2 + colL;        // global gate row
    const float* wih = dir ? wih_b : wih_f;
    const float* whh = dir ? whh_b : whh_f;
    const float v = sec ? whh[(size_t)rg * 512 + k] : wih[(size_t)rg * 512 + k];
    wpack[i] = v;
}

// ---------------------------------------------------------------------------
// K1: persistent BiLSTM recurrence. 512 WGs (256/dir) x 512 threads.
// WG owns 2 h-cols (8 gate rows). lane = b, wave = k-slice (split-k x8).
// All weights in LDS; packed-f32 FMA. Per-wave dataflow sync.
// ---------------------------------------------------------------------------
__global__ __launch_bounds__(512, 2) void k_lstm(
    const float4* __restrict__ eg4, const float* __restrict__ wpack,
    const float* __restrict__ b_f, const float* __restrict__ b_b,
    float* __restrict__ h_f, float* __restrict__ h_b,
    int* __restrict__ bar)
{
    const int bid = blockIdx.x;
    const int dir = bid >> 8;
    const int wg  = bid & 255;
    float* HH       = dir ? h_b : h_f;
    const float* BS = dir ? b_b : b_f;
    int* ctr = bar + (size_t)dir * 65536;   // [step][sub:8] x 16 ints

    const int tid = threadIdx.x;
    const int b   = tid & 63;
    const int ks  = __builtin_amdgcn_readfirstlane(tid >> 6);   // 0..7

    __shared__ float wlds[8][1024];     // 32 KB: per-wave [sec0:512|sec1:512]
    __shared__ float partb[8 * 8 * 64]; // 16 KB split-k exchange
    __shared__ float hlds[64][2];       // h staging for coalesced store

    // ---- stage this wave's weights into LDS once (1024 f32) ----
    {
        const float4* src = reinterpret_cast<const float4*>(
            wpack + (size_t)((dir * 256 + wg) * 8 + ks) * 1024);
        float4* dst = reinterpret_cast<float4*>(&wlds[ks][0]);
        #pragma unroll
        for (int i = 0; i < 4; ++i)
            dst[i * 64 + b] = src[i * 64 + b];
    }

    const int colL = (tid >> 6) & 1;    // gate-phase col (tid<128)
    float bias4[4] = {0.f, 0.f, 0.f, 0.f};
    if (tid < 128) {
        #pragma unroll
        for (int g = 0; g < 4; ++g) bias4[g] = BS[g * 512 + wg * 2 + colL];
    }
    float cst = 0.f;
    __syncthreads();                    // wlds ready

    const float* wl = &wlds[ks][0];

    // packed e-accumulator for the upcoming step (lo=even-k, hi=odd-k)
    f32x2 eacc2[8];
    #pragma unroll
    for (int r = 0; r < 8; ++r) eacc2[r] = (f32x2){0.f, 0.f};

    // prologue: e-part for step 0
    {
        const int t0 = dir ? 511 : 0;
        const float4* ep = eg4 + ((size_t)t0 * 128 + ks * 16) * 64 + b;
        #pragma unroll
        for (int half = 0; half < 2; ++half) {
            f32x4 v[8];
            #pragma unroll
            for (int kc = 0; kc < 8; ++kc)
                v[kc] = *reinterpret_cast<const f32x4*>(ep + (size_t)(half * 8 + kc) * 64);
            #pragma unroll
            for (int kc = 0; kc < 8; ++kc) {
                const float* wp = wl + (half * 8 + kc) * 32;
                const f32x2 elo = __builtin_shufflevector(v[kc], v[kc], 0, 1);
                const f32x2 ehi = __builtin_shufflevector(v[kc], v[kc], 2, 3);
                #pragma unroll
                for (int r = 0; r < 8; ++r) {
                    const f32x4 w4 = *reinterpret_cast<const f32x4*>(wp + r * 4);
                    const f32x2 wlo = __builtin_shufflevector(w4, w4, 0, 1);
                    const f32x2 whi = __builtin_shufflevector(w4, w4, 2, 3);
                    PKFMA(eacc2[r], wlo, elo);
                    PKFMA(eacc2[r], whi, ehi);
                }
            }
        }
    }

    for (int s = 0; s < 512; ++s) {
        const int t = dir ? (511 - s) : s;
        f32x2 acc2[8];
        #pragma unroll
        for (int r = 0; r < 8; ++r) acc2[r] = eacc2[r];

        // ---- per-wave wait on sub ks, then h-dot (LDS weights, pk fma) ----
        if (s > 0) {
            const int* fp = ctr + ((size_t)(s - 1) * 8 + ks) * 16;
            while (__hip_atomic_load(fp, __ATOMIC_RELAXED,
                                     __HIP_MEMORY_SCOPE_AGENT) < 32)
                __builtin_amdgcn_s_sleep(1);

            const int tp = dir ? (t + 1) : (t - 1);
            const f32x2* hq = reinterpret_cast<const f32x2*>(HH)
                              + ((size_t)tp * 256 + ks * 32) * 64 + b;
            #pragma unroll
            for (int half = 0; half < 2; ++half) {
                f32x2 hv[16];
                #pragma unroll
                for (int kq = 0; kq < 16; ++kq)
                    hv[kq] = hq[(size_t)(half * 16 + kq) * 64];
                #pragma unroll
                for (int kc = 0; kc < 8; ++kc) {
                    const float* wp = wl + 512 + (half * 8 + kc) * 32;
                    #pragma unroll
                    for (int r = 0; r < 8; ++r) {
                        const f32x4 w4 = *reinterpret_cast<const f32x4*>(wp + r * 4);
                        const f32x2 wlo = __builtin_shufflevector(w4, w4, 0, 1);
                        const f32x2 whi = __builtin_shufflevector(w4, w4, 2, 3);
                        PKFMA(acc2[r], wlo, hv[kc * 2]);
                        PKFMA(acc2[r], whi, hv[kc * 2 + 1]);
                    }
                }
            }
        }

        // ---- split-k reduce (horizontal add once per row) ----
        #pragma unroll
        for (int r = 0; r < 8; ++r)
            partb[(ks * 8 + r) * 64 + b] = acc2[r][0] + acc2[r][1];
        __syncthreads();                 // sync1: part ready

        // ---- gates (tid<128: colL x b) ----
        if (tid < 128) {
            float g4[4];
            #pragma unroll
            for (int g = 0; g < 4; ++g) {
                const int r = g * 2 + colL;
                float v = bias4[g];
                #pragma unroll
                for (int w = 0; w < 8; ++w) v += partb[(w * 8 + r) * 64 + b];
                g4[g] = v;
            }
            const float si = 1.f / (1.f + expf(-g4[0]));
            const float sf = 1.f / (1.f + expf(-g4[1]));
            const float tg = tanhf(g4[2]);
            const float so = 1.f / (1.f + expf(-g4[3]));
            cst = sf * cst + si * tg;
            hlds[b][colL] = so * tanhf(cst);
        }
        __syncthreads();                 // sync2: hlds ready, part consumed

        // ---- wave0: contiguous sc1 dwordx2 store, drain, publish ----
        if (tid < 64) {
            f32x2 o;
            o[0] = hlds[tid][0]; o[1] = hlds[tid][1];
            float* dst = HH + (((size_t)t * 256 + wg) * 64 + tid) * 2;
            asm volatile("global_store_dwordx2 %0, %1, off sc1"
                         :: "v"(dst), "v"(o) : "memory");
            asm volatile("s_waitcnt vmcnt(0)" ::: "memory");
            if (tid == 0 && s < 511)
                __hip_atomic_fetch_add(
                    ctr + ((size_t)s * 8 + (wg >> 5)) * 16, 1,
                    __ATOMIC_RELAXED, __HIP_MEMORY_SCOPE_AGENT);
        }

        // ---- e-part for step s+1 (LDS weights; off critical path) ----
        if (s < 511) {
            const int tn = dir ? (t - 1) : (t + 1);
            const float4* ep = eg4 + ((size_t)tn * 128 + ks * 16) * 64 + b;
            #pragma unroll
            for (int r = 0; r < 8; ++r) eacc2[r] = (f32x2){0.f, 0.f};
            #pragma unroll
            for (int half = 0; half < 2; ++half) {
                f32x4 v[8];
                #pragma unroll
                for (int kc = 0; kc < 8; ++kc)
                    v[kc] = *reinterpret_cast<const f32x4*>(ep + (size_t)(half * 8 + kc) * 64);
                #pragma unroll
                for (int kc = 0; kc < 8; ++kc) {
                    const float* wp = wl + (half * 8 + kc) * 32;
                    const f32x2 elo = __builtin_shufflevector(v[kc], v[kc], 0, 1);
                    const f32x2 ehi = __builtin_shufflevector(v[kc], v[kc], 2, 3);
                    #pragma unroll
                    for (int r = 0; r < 8; ++r) {
                        const f32x4 w4 = *reinterpret_cast<const f32x4*>(wp + r * 4);
                        const f32x2 wlo = __builtin_shufflevector(w4, w4, 0, 1);
                        const f32x2 whi = __builtin_shufflevector(w4, w4, 2, 3);
                        PKFMA(eacc2[r], wlo, elo);
                        PKFMA(eacc2[r], whi, ehi);
                    }
                }
            }
        }
    }
}

// ---------------------------------------------------------------------------
// K2: emissions  em[t][b][tag] = [hf;hb](t,b,:) . W[tag][:] + bias
// h layout [t][c2][b][2]
// ---------------------------------------------------------------------------
__global__ __launch_bounds__(256) void k_em(
    const float* __restrict__ hf, const float* __restrict__ hb,
    const float* __restrict__ Wm, const float* __restrict__ bias,
    float* __restrict__ em)
{
    const int t   = blockIdx.x;
    const int tid = threadIdx.x;
    const int b   = tid & 63;
    const int tg  = tid >> 6;          // 0..3 -> tags [tg*8, tg*8+8)
    __shared__ float Wl[128][33];
    float acc[8] = {};

    for (int ch = 0; ch < 8; ++ch) {
        {
            const int tag = tid >> 3;   // 0..31
            const int kq  = tid & 7;    // 0..7
            const float* src = Wm + (size_t)tag * 1024 + ch * 128 + kq * 16;
            #pragma unroll
            for (int ii = 0; ii < 4; ++ii) {
                const float4 v = *reinterpret_cast<const float4*>(src + ii * 4);
                const int k0 = kq * 16 + ii * 4;
                Wl[k0 + 0][tag] = v.x; Wl[k0 + 1][tag] = v.y;
                Wl[k0 + 2][tag] = v.z; Wl[k0 + 3][tag] = v.w;
            }
        }
        __syncthreads();
        const f32x2* hsrc2 = (ch < 4)
            ? (reinterpret_cast<const f32x2*>(hf) + ((size_t)t * 256 + ch * 64) * 64 + b)
            : (reinterpret_cast<const f32x2*>(hb) + ((size_t)t * 256 + (ch - 4) * 64) * 64 + b);
        #pragma unroll 4
        for (int c2l = 0; c2l < 64; ++c2l) {
            const f32x2 h2 = hsrc2[(size_t)c2l * 64];
            #pragma unroll
            for (int j = 0; j < 2; ++j)
                #pragma unroll
                for (int jt = 0; jt < 8; ++jt)
                    acc[jt] = fmaf(h2[j], Wl[c2l * 2 + j][tg * 8 + jt], acc[jt]);
        }
        __syncthreads();
    }

    #pragma unroll
    for (int jt = 0; jt < 8; ++jt) {
        const int tag = tg * 8 + jt;
        em[((size_t)t * 64 + b) * 32 + tag] = acc[jt] + bias[tag];
    }
}

// ---------------------------------------------------------------------------
// K3: Viterbi forward + backtrace, one wave per batch row.
// ---------------------------------------------------------------------------
__global__ __launch_bounds__(64) void k_vit(
    const float* __restrict__ em, const float* __restrict__ startv,
    const float* __restrict__ endv, const float* __restrict__ trans,
    int* __restrict__ out)
{
    const int b    = blockIdx.x;
    const int lane = threadIdx.x;
    const int c    = lane & 31;
    const bool act = lane < 32;
    __shared__ unsigned char hist[511][32];
    __shared__ int outb[512];

    float tr[32];
    #pragma unroll 8
    for (int p = 0; p < 32; ++p) tr[p] = trans[p * 32 + c];

    float s = act ? (startv[c] + em[(size_t)b * 32 + c]) : -1e30f;

    for (int t = 1; t < 512; ++t) {
        const float emc = act ? em[((size_t)t * 64 + b) * 32 + c] : 0.f;
        float m = -1e30f; int arg = 0;
        #pragma unroll 8
        for (int p = 0; p < 32; ++p) {
            const float v = __shfl(s, p) + tr[p] + emc;   // (s+tr)+em, ref order
            if (v > m) { m = v; arg = p; }                // strict > => first max
        }
        if (act) { s = m; hist[t - 1][c] = (unsigned char)arg; }
    }

    s = act ? (s + endv[c]) : -1e30f;
    int idx = act ? c : 63;
    #pragma unroll
    for (int off = 32; off >= 1; off >>= 1) {
        const float om = __shfl_down(s, off);
        const int   oi = __shfl_down(idx, off);
        if (om > s || (om == s && oi < idx)) { s = om; idx = oi; }
    }
    idx = __shfl(idx, 0);

    if (lane == 0) {
        int tag = idx;
        outb[511] = tag;
        for (int t = 510; t >= 0; --t) { tag = hist[t][tag]; outb[t] = tag; }
    }
    __syncthreads();
    for (int i = lane; i < 512; i += 64) out[(size_t)b * 512 + i] = outb[i];
}

// ---------------------------------------------------------------------------
extern "C" void kernel_launch(void* const* d_in, const int* in_sizes, int n_in,
                              void* d_out, int out_size, void* d_ws, size_t ws_size,
                              hipStream_t stream)
{
    const int*   x      = (const int*)d_in[0];
    const float* emb    = (const float*)d_in[1];
    const float* w_ih_f = (const float*)d_in[2];
    const float* w_hh_f = (const float*)d_in[3];
    const float* b_f    = (const float*)d_in[4];
    const float* w_ih_b = (const float*)d_in[5];
    const float* w_hh_b = (const float*)d_in[6];
    const float* b_b    = (const float*)d_in[7];
    const float* Wm     = (const float*)d_in[8];
    const float* bvec   = (const float*)d_in[9];
    const float* startv = (const float*)d_in[10];
    const float* endv   = (const float*)d_in[11];
    const float* trans  = (const float*)d_in[12];
    int* out = (int*)d_out;

    float* ws    = (float*)d_ws;
    float* eg    = ws;                          // 16,777,216 f32 (64 MB)
    float* h_f   = ws + 16777216;               // 16,777,216 f32
    float* h_b   = ws + 33554432;               // 16,777,216 f32
    float* em    = ws + 50331648;               //  1,048,576 f32
    float* wpack = ws + 51380224;               //  4,194,304 f32 (16 MB)
    int*   bar   = (int*)(ws + 55574528);       //  131,072 ints (512 KB)

    const size_t need = (size_t)(55574528 + 131072) * 4;
    if (ws_size < need) {
        fprintf(stderr, "kernel_launch: ws too small: %zu < %zu\n", ws_size, need);
        return;
    }

    (void)hipMemsetAsync(bar, 0, 524288, stream);
    k_gather<<<dim3(512),   512, 0, stream>>>(x, emb, (float4*)eg);
    k_pack  <<<dim3(16384), 256, 0, stream>>>(w_ih_f, w_hh_f, w_ih_b, w_hh_b, wpack);
    k_lstm  <<<dim3(512),   512, 0, stream>>>((const float4*)eg, wpack, b_f, b_b,
                                              h_f, h_b, bar);
    k_em    <<<dim3(512),   256, 0, stream>>>(h_f, h_b, Wm, bvec, em);
    k_vit   <<<dim3(64),     64, 0, stream>>>(em, startv, endv, trans, out);
}